// Round 1
// 329.459 us; speedup vs baseline: 1.0358x; 1.0358x over previous
//
#include <hip/hip_runtime.h>
#include <hip/hip_bf16.h>
#include <math.h>

#define L_SEQ 2048
#define DIM   2048
#define NH    16
#define HD    128
#define TDIM  6144

typedef __attribute__((ext_vector_type(8))) short short8;
typedef __attribute__((ext_vector_type(4))) float f32x4;
typedef __attribute__((ext_vector_type(4))) unsigned int u32x4;

// async global->LDS, 16 B per lane. LDS dest = wave-uniform base + lane*16.
__device__ __forceinline__ void gl_lds16(const void* g, void* l) {
  __builtin_amdgcn_global_load_lds(
      (const __attribute__((address_space(1))) unsigned int*)g,
      (__attribute__((address_space(3))) unsigned int*)l, 16, 0, 0);
}

__device__ __forceinline__ short bf16bits(float x) {
  __hip_bfloat16 h = __float2bfloat16(x);
  return *(short*)&h;
}

__device__ __forceinline__ float bits2f(short s) {
  unsigned int u = ((unsigned int)(unsigned short)s) << 16;
  return __uint_as_float(u);
}

__device__ __forceinline__ unsigned int pack_bf16(float a, float b) {
  __hip_bfloat162 h = __float22bfloat162_rn(make_float2(a, b));
  return *(unsigned int*)&h;
}

// ---------------------------------------------------------------------------
// fused fp32 -> bf16 cast of x (4M elems) then qkv_w (12M elems).
// ---------------------------------------------------------------------------
__global__ __launch_bounds__(256)
void cast2_bf16(const float* __restrict__ a, __hip_bfloat16* __restrict__ oa,
                const float* __restrict__ b, __hip_bfloat16* __restrict__ ob) {
  int i = (blockIdx.x * 256 + threadIdx.x) * 8;
  const float* src;
  __hip_bfloat16* dst;
  int off;
  if (i < DIM * DIM) { src = a; dst = oa; off = i; }
  else               { src = b; dst = ob; off = i - DIM * DIM; }
  float4 v0 = *(const float4*)(src + off);
  float4 v1 = *(const float4*)(src + off + 4);
  short8 o;
  o[0] = bf16bits(v0.x); o[1] = bf16bits(v0.y); o[2] = bf16bits(v0.z); o[3] = bf16bits(v0.w);
  o[4] = bf16bits(v1.x); o[5] = bf16bits(v1.y); o[6] = bf16bits(v1.z); o[7] = bf16bits(v1.w);
  *(short8*)(dst + off) = o;
}

__global__ __launch_bounds__(256)
void cast_bf16(const float* __restrict__ in, __hip_bfloat16* __restrict__ out, int n) {
  int i = (blockIdx.x * 256 + threadIdx.x) * 8;
  if (i >= n) return;
  float4 a = *(const float4*)(in + i);
  float4 b = *(const float4*)(in + i + 4);
  short8 o;
  o[0] = bf16bits(a.x); o[1] = bf16bits(a.y); o[2] = bf16bits(a.z); o[3] = bf16bits(a.w);
  o[4] = bf16bits(b.x); o[5] = bf16bits(b.y); o[6] = bf16bits(b.z); o[7] = bf16bits(b.w);
  *(short8*)(out + i) = o;
}

// ---------------------------------------------------------------------------
// QKV GEMM, deep-pipelined 256x256 tile (T3+T4+T5).
//   BM=BN=256, BK=32, 4-deep LDS ring (4 x 32 KB = 128 KiB dynamic LDS).
//   512 threads = 8 waves (2M x 4N); per-wave C: 128x64 (acc[8][4]).
//   Per K-tile: 2 phases of 16 MFMA; stage tile t+3 (4 x gl_lds16);
//   ONE counted s_waitcnt vmcnt(8) fused with raw s_barrier per tile
//   (never drains to 0 in the main loop).
//   LDS [256][32] layout => fragment reads are contiguous 1KB/wave =>
//   conflict-free without swizzle; staging is linear (gl_lds-compatible).
//   Writes plain bf16 C[2048][6144]; norm/rope/transpose in qkv_epilogue.
// ---------------------------------------------------------------------------
#define QKV_N 6144
#define QKV_K 2048

__global__ __launch_bounds__(512, 2)
void gemm_qkv_256(const __hip_bfloat16* __restrict__ A,
                  const __hip_bfloat16* __restrict__ B,
                  __hip_bfloat16* __restrict__ C) {
  extern __shared__ char smem[];
  const int tid  = threadIdx.x;
  const int lane = tid & 63, w = tid >> 6;
  const int l15  = lane & 15, quad = lane >> 4;
  const int wm   = w >> 2, wn = w & 3;

  // XCD-aware swizzle: 192 blocks, nwg % 8 == 0 -> by = xcd (A-panel/XCD)
  const int orig = blockIdx.x;
  const int by = orig & 7;    // M-tile: 8 tiles of 256
  const int bx = orig >> 3;   // N-tile: 24 tiles of 256
  const int m0 = by * 256, n0 = bx * 256;

  // staging: chunk idx = round*512 + tid; row = idx>>2, q = idx&3 (16B chunks)
  const int ar0 = tid >> 2,         aq0 = tid & 3;
  const int ar1 = (512 + tid) >> 2, aq1 = (512 + tid) & 3;
  const __hip_bfloat16* pA0 = A + (size_t)(m0 + ar0) * QKV_K + aq0 * 8;
  const __hip_bfloat16* pA1 = A + (size_t)(m0 + ar1) * QKV_K + aq1 * 8;
  const __hip_bfloat16* pB0 = B + (size_t)(n0 + ar0) * QKV_K + aq0 * 8;
  const __hip_bfloat16* pB1 = B + (size_t)(n0 + ar1) * QKV_K + aq1 * 8;
  const int dst0 = w * 1024;  // wave-uniform LDS byte base, round 0

  f32x4 acc[8][4];
#pragma unroll
  for (int mi = 0; mi < 8; ++mi)
#pragma unroll
    for (int ni = 0; ni < 4; ++ni) acc[mi][ni] = (f32x4){0.f, 0.f, 0.f, 0.f};

  // fragment read byte offsets within a buffer
  const int aoff = ((wm * 128 + l15) * 32 + quad * 8) * 2;
  const int boff = ((wn * 64 + l15) * 32 + quad * 8) * 2;

  // prologue: stage tiles 0,1,2 into bufs 0,1,2 (12 loads); publish tile 0
#pragma unroll
  for (int p = 0; p < 3; ++p) {
    char* Sp = smem + p * 32768;
    gl_lds16(pA0 + p * 32, Sp + dst0);
    gl_lds16(pA1 + p * 32, Sp + dst0 + 8192);
    gl_lds16(pB0 + p * 32, Sp + 16384 + dst0);
    gl_lds16(pB1 + p * 32, Sp + 16384 + dst0 + 8192);
  }
  asm volatile("s_waitcnt vmcnt(8)\n\ts_barrier" ::: "memory");

  for (int tb = 0; tb < 64; tb += 4) {
#pragma unroll
    for (int u = 0; u < 4; ++u) {
      const int t  = tb + u;
      const char* As = smem + u * 32768;          // buf = t & 3 == u
      const char* Bs = As + 16384;
      const int tn = (t + 3) & 63;                // tile to stage (wrap-safe)
      char* Sn = smem + ((u + 3) & 3) * 32768;    // its buffer (freed @ t-1 end)

      // ---- phase A: read A-frags + B n-half0, stage A(t+3), MFMA x16 ----
      short8 a[8];
#pragma unroll
      for (int mi = 0; mi < 8; ++mi)
        a[mi] = *(const short8*)(As + aoff + mi * 1024);
      short8 b0 = *(const short8*)(Bs + boff);
      short8 b1 = *(const short8*)(Bs + boff + 1024);
      gl_lds16(pA0 + tn * 32, Sn + dst0);
      gl_lds16(pA1 + tn * 32, Sn + dst0 + 8192);
      __builtin_amdgcn_s_barrier();
      __builtin_amdgcn_s_setprio(1);
#pragma unroll
      for (int mi = 0; mi < 8; ++mi) {
        acc[mi][0] = __builtin_amdgcn_mfma_f32_16x16x32_bf16(a[mi], b0, acc[mi][0], 0, 0, 0);
        acc[mi][1] = __builtin_amdgcn_mfma_f32_16x16x32_bf16(a[mi], b1, acc[mi][1], 0, 0, 0);
      }
      __builtin_amdgcn_s_setprio(0);
      __builtin_amdgcn_s_barrier();

      // ---- phase B: read B n-half1, stage B(t+3), publish tile t+1 ----
      short8 b2 = *(const short8*)(Bs + boff + 2048);
      short8 b3 = *(const short8*)(Bs + boff + 3072);
      gl_lds16(pB0 + tn * 32, Sn + 16384 + dst0);
      gl_lds16(pB1 + tn * 32, Sn + 16384 + dst0 + 8192);
      // counted wait: newest 8 loads (tiles t+2, t+3) stay in flight;
      // everything older (incl. tile t+1's 4) is complete. Fused with the
      // barrier in one asm so it is also the compiler memory fence.
      asm volatile("s_waitcnt vmcnt(8)\n\ts_barrier" ::: "memory");
      __builtin_amdgcn_s_setprio(1);
#pragma unroll
      for (int mi = 0; mi < 8; ++mi) {
        acc[mi][2] = __builtin_amdgcn_mfma_f32_16x16x32_bf16(a[mi], b2, acc[mi][2], 0, 0, 0);
        acc[mi][3] = __builtin_amdgcn_mfma_f32_16x16x32_bf16(a[mi], b3, acc[mi][3], 0, 0, 0);
      }
      __builtin_amdgcn_s_setprio(0);
      __builtin_amdgcn_s_barrier();
    }
  }

  // C write (bf16 scalar stores; L2 merges partial lines)
  const int crow = m0 + wm * 128 + quad * 4;
  const int ccol = n0 + wn * 64 + l15;
#pragma unroll
  for (int mi = 0; mi < 8; ++mi)
#pragma unroll
    for (int ni = 0; ni < 4; ++ni)
#pragma unroll
      for (int r = 0; r < 4; ++r)
        C[(size_t)(crow + mi * 16 + r) * QKV_N + ccol + ni * 16] =
            __float2bfloat16(acc[mi][ni][r]);
}

// ---------------------------------------------------------------------------
// Epilogue: reads C[2048][6144] bf16 (L3-resident).
//  blocks [0,512):  q/k -> RMSNorm + RoPE (+1/sqrt(HD) for q) -> Qb/Kb[h][l][d]
//    (verified R6/R8 per-row math, reading the contiguous row slice from C)
//  blocks [512,1024): v -> LDS transpose -> Vt[h][d][l]
// ---------------------------------------------------------------------------
__global__ __launch_bounds__(256)
void qkv_epilogue(const __hip_bfloat16* __restrict__ C,
                  const float* __restrict__ q_scale, const float* __restrict__ k_scale,
                  const float* __restrict__ pe,
                  __hip_bfloat16* __restrict__ Qb, __hip_bfloat16* __restrict__ Kb,
                  __hip_bfloat16* __restrict__ Vt) {
  const int bid = blockIdx.x;
  const int t = threadIdx.x;
  if (bid < 512) {
    const int sec = bid >> 8;          // 0 = q, 1 = k
    const int h   = (bid >> 4) & 15;
    const int rb  = bid & 15;          // 16 row-blocks of 128
    const float* scale = sec ? k_scale : q_scale;
    const float qmul = sec ? 1.0f : 0.08838834764831845f;
    __hip_bfloat16* dst = sec ? Kb : Qb;

    const int row = t >> 1, half = t & 1;
    const int l = rb * 128 + row;
    const __hip_bfloat16* grow = C + (size_t)l * TDIM + sec * DIM + h * HD + half * 64;

    float ss = 0.f;
#pragma unroll
    for (int c8 = 0; c8 < 64; c8 += 8) {
      short8 v8 = *(const short8*)(grow + c8);
#pragma unroll
      for (int j = 0; j < 8; ++j) { float f = bits2f(v8[j]); ss += f * f; }
    }
    ss += __shfl_xor(ss, 1);   // partner thread = other half, same row
    const float rrms = rsqrtf(ss * (1.f / 128.f) + 1e-6f);

    const float* perow = pe + (size_t)l * 256 + half * 128;
    __hip_bfloat16* drow = dst + ((size_t)h * L_SEQ + l) * HD + half * 64;

#pragma unroll
    for (int c8 = 0; c8 < 64; c8 += 8) {
      short8 v8 = *(const short8*)(grow + c8);
      float f[8];
#pragma unroll
      for (int j = 0; j < 8; ++j)
        f[j] = bits2f(v8[j]) * rrms * scale[half * 64 + c8 + j];
      short8 o;
#pragma unroll
      for (int p = 0; p < 4; ++p) {
        float4 pp = *(const float4*)(perow + c8 * 2 + p * 4);
        float e = f[2 * p], od = f[2 * p + 1];
        o[2 * p]     = bf16bits((pp.x * e + pp.y * od) * qmul);
        o[2 * p + 1] = bf16bits((pp.z * e + pp.w * od) * qmul);
      }
      *(short8*)(drow + c8) = o;
    }
  } else {
    __shared__ short Tt[128 * 72];
    const int vb = bid - 512;
    const int h = vb >> 5, lb = vb & 31;
    const int l0 = lb * 64;
#pragma unroll
    for (int k = 0; k < 4; ++k) {
      int idx = t + k * 256;
      int row = idx >> 4, c = idx & 15;
      short8 v = *(const short8*)(C + (size_t)(l0 + row) * TDIM + 2 * DIM + h * HD + c * 8);
#pragma unroll
      for (int j = 0; j < 8; ++j) Tt[(c * 8 + j) * 72 + row] = v[j];
    }
    __syncthreads();
    const int d = t >> 1, lh = t & 1;
    __hip_bfloat16* vrow = Vt + ((size_t)h * HD + d) * L_SEQ + l0 + lh * 32;
#pragma unroll
    for (int k = 0; k < 4; ++k) {
      short8 o = *(const short8*)&Tt[d * 72 + lh * 32 + k * 8];
      *(short8*)(vrow + k * 8) = o;
    }
  }
}

// ---------------------------------------------------------------------------
// bf16 MFMA GEMM (m97 structure) — proj only (fp32 out + bias). Verified.
// ---------------------------------------------------------------------------
__global__ __launch_bounds__(256)
void gemm_proj(const __hip_bfloat16* __restrict__ A, const __hip_bfloat16* __restrict__ B,
               const float* __restrict__ bias, float* __restrict__ C,
               int M, int N, int K) {
  const int n0 = blockIdx.x * 128, m0 = blockIdx.y * 128;
  const int t = threadIdx.x, lane = t & 63, w = t >> 6;
  const int l15 = lane & 15, quad = lane >> 4;
  const int wm = (w & 1) * 64, wn = (w >> 1) * 64;

  __shared__ __align__(16) __hip_bfloat16 As[128 * 32];
  __shared__ __align__(16) __hip_bfloat16 Bs[128 * 32];

  f32x4 acc[4][4];
#pragma unroll
  for (int mt = 0; mt < 4; ++mt)
#pragma unroll
    for (int nt = 0; nt < 4; ++nt) acc[mt][nt] = (f32x4){0.f, 0.f, 0.f, 0.f};

  const int arow  = lane >> 2;
  const int acol8 = (lane & 3) * 8;
  const __hip_bfloat16* Ab = A + (size_t)(m0 + w * 16 + arow) * K + acol8;
  const __hip_bfloat16* Bb = B + (size_t)(n0 + w * 16 + arow) * K + acol8;
  __hip_bfloat16* As_base = As + (size_t)(w * 16) * 32;
  __hip_bfloat16* Bs_base = Bs + (size_t)(w * 16) * 32;

  for (int kb = 0; kb < K; kb += 32) {
    gl_lds16(Ab + kb,                As_base);
    gl_lds16(Ab + kb + (size_t)64*K, As_base + 64 * 32);
    gl_lds16(Bb + kb,                Bs_base);
    gl_lds16(Bb + kb + (size_t)64*K, Bs_base + 64 * 32);
    __syncthreads();

    short8 am[4], bn[4];
#pragma unroll
    for (int mt = 0; mt < 4; ++mt)
      am[mt] = *(const short8*)&As[(size_t)(wm + mt*16 + l15) * 32 + quad * 8];
#pragma unroll
    for (int nt = 0; nt < 4; ++nt)
      bn[nt] = *(const short8*)&Bs[(size_t)(wn + nt*16 + l15) * 32 + quad * 8];
#pragma unroll
    for (int mt = 0; mt < 4; ++mt)
#pragma unroll
      for (int nt = 0; nt < 4; ++nt)
        acc[mt][nt] = __builtin_amdgcn_mfma_f32_16x16x32_bf16(am[mt], bn[nt], acc[mt][nt], 0, 0, 0);
    __syncthreads();
  }

#pragma unroll
  for (int mt = 0; mt < 4; ++mt)
#pragma unroll
    for (int nt = 0; nt < 4; ++nt) {
      int col = n0 + wn + nt * 16 + l15;
#pragma unroll
      for (int r = 0; r < 4; ++r) {
        int row = m0 + wm + mt * 16 + quad * 4 + r;
        C[(size_t)row * N + col] = acc[mt][nt][r] + bias[col];
      }
    }
}

// ---------------------------------------------------------------------------
// Flash attention: KV-split (grid.z=2), S^T formulation — verified R6.
// ---------------------------------------------------------------------------
__global__ __launch_bounds__(256, 4)
void attn_mfma(const __hip_bfloat16* __restrict__ Qb,
               const __hip_bfloat16* __restrict__ Kb,
               const __hip_bfloat16* __restrict__ Vt,
               __hip_bfloat16* __restrict__ Opart, float2* __restrict__ ml) {
  const int q0 = blockIdx.x * 64;
  const int h  = blockIdx.y;
  const int z  = blockIdx.z;
  const int t  = threadIdx.x;
  const int lane = t & 63, w = t >> 6;
  const int l15 = lane & 15, quad = lane >> 4;
  const int sw = l15 & 7;

  __shared__ __align__(16) __hip_bfloat16 Ks[64 * 128];
  __shared__ __align__(16) __hip_bfloat16 Vs[128 * 64];

  const __hip_bfloat16* kbase = Kb + (size_t)h * L_SEQ * HD;
  const __hip_bfloat16* vbase = Vt + (size_t)h * HD * L_SEQ;

  short8 aq[4];
  {
    const __hip_bfloat16* qbase = Qb + ((size_t)h * L_SEQ + q0 + w * 16 + l15) * HD;
#pragma unroll
    for (int ks = 0; ks < 4; ++ks)
      aq[ks] = *(const short8*)(qbase + ks * 32 + quad * 8);
  }

  f32x4 o[8];
#pragma unroll
  for (int n2 = 0; n2 < 8; ++n2) o[n2] = (f32x4){0.f, 0.f, 0.f, 0.f};
  float m_run = -1e30f, l_run = 0.f;

  for (int kt = 0; kt < 16; ++kt) {
    const int k0 = z * (L_SEQ / 2) + kt * 64;
#pragma unroll
    for (int i = 0; i < 4; ++i) {
      int krow = w * 16 + i * 4 + (lane >> 4);
      int kch  = (lane & 15) ^ (krow & 7);
      gl_lds16(kbase + (size_t)(k0 + krow) * HD + kch * 8,
               &Ks[(w * 16 + i * 4) * 128]);
    }
#pragma unroll
    for (int i = 0; i < 4; ++i) {
      int vrow = w * 32 + i * 8 + (lane >> 3);
      int vch  = (lane & 7) ^ (vrow & 7);
      gl_lds16(vbase + (size_t)vrow * L_SEQ + k0 + vch * 8,
               &Vs[(w * 32 + i * 8) * 64]);
    }
    __syncthreads();

    f32x4 s[4];
#pragma unroll
    for (int nt = 0; nt < 4; ++nt) s[nt] = (f32x4){0.f, 0.f, 0.f, 0.f};
#pragma unroll
    for (int ks = 0; ks < 4; ++ks) {
      short8 bk[4];
#pragma unroll
      for (int nt = 0; nt < 4; ++nt)
        bk[nt] = *(const short8*)&Ks[(nt * 16 + l15) * 128 + ((ks * 4 + quad) ^ sw) * 8];
#pragma unroll
      for (int nt = 0; nt < 4; ++nt)
        s[nt] = __builtin_amdgcn_mfma_f32_16x16x32_bf16(bk[nt], aq[ks], s[nt], 0, 0, 0);
    }

    float mx0 = fmaxf(fmaxf(s[0][0], s[0][1]), fmaxf(s[0][2], s[0][3]));
    float mx1 = fmaxf(fmaxf(s[1][0], s[1][1]), fmaxf(s[1][2], s[1][3]));
    float mx2 = fmaxf(fmaxf(s[2][0], s[2][1]), fmaxf(s[2][2], s[2][3]));
    float mx3 = fmaxf(fmaxf(s[3][0], s[3][1]), fmaxf(s[3][2], s[3][3]));
    float rm = fmaxf(fmaxf(mx0, mx1), fmaxf(mx2, mx3));
    rm = fmaxf(rm, __shfl_xor(rm, 16));
    rm = fmaxf(rm, __shfl_xor(rm, 32));
    float mnew = fmaxf(m_run, rm);
    float alpha = __expf(m_run - mnew);
    m_run = mnew;

    float sum = 0.f;
#pragma unroll
    for (int nt = 0; nt < 4; ++nt)
#pragma unroll
      for (int r = 0; r < 4; ++r) {
        float p = __expf(s[nt][r] - mnew);
        s[nt][r] = p;
        sum += p;
      }
    sum += __shfl_xor(sum, 16);
    sum += __shfl_xor(sum, 32);
    l_run = l_run * alpha + sum;

    float alpha_r[4];
#pragma unroll
    for (int r = 0; r < 4; ++r) alpha_r[r] = __shfl(alpha, quad * 4 + r);
#pragma unroll
    for (int n2 = 0; n2 < 8; ++n2)
#pragma unroll
      for (int r = 0; r < 4; ++r) o[n2][r] *= alpha_r[r];

    unsigned int pk[4][2];
#pragma unroll
    for (int nt = 0; nt < 4; ++nt) {
      pk[nt][0] = pack_bf16(s[nt][0], s[nt][1]);
      pk[nt][1] = pack_bf16(s[nt][2], s[nt][3]);
    }
    short8 ap[2];
#pragma unroll
    for (int ks2 = 0; ks2 < 2; ++ks2) {
      u32x4 a32;
#pragma unroll
      for (int jp = 0; jp < 4; ++jp) {
        int quad_src = (quad & 1) * 2 + (jp >> 1);
        int src = (quad_src << 4) | l15;
        int rp = jp & 1;
        unsigned int v0 = __shfl((int)pk[2 * ks2 + 0][rp], src);
        unsigned int v1 = __shfl((int)pk[2 * ks2 + 1][rp], src);
        a32[jp] = (quad >> 1) ? v1 : v0;
      }
      ap[ks2] = *(short8*)&a32;
    }

#pragma unroll
    for (int ks2 = 0; ks2 < 2; ++ks2)
#pragma unroll
      for (int n2 = 0; n2 < 8; ++n2) {
        short8 bv = *(const short8*)&Vs[(n2 * 16 + l15) * 64 + ((ks2 * 4 + quad) ^ sw) * 8];
        o[n2] = __builtin_amdgcn_mfma_f32_16x16x32_bf16(ap[ks2], bv, o[n2], 0, 0, 0);
      }

    __syncthreads();
  }

  const size_t rb = (size_t)(z * NH + h) * L_SEQ + q0 + w * 16;
  float linv[4];
#pragma unroll
  for (int r = 0; r < 4; ++r) linv[r] = 1.f / __shfl(l_run, quad * 4 + r);
#pragma unroll
  for (int r = 0; r < 4; ++r) {
    size_t row = rb + quad * 4 + r;
#pragma unroll
    for (int n2 = 0; n2 < 8; ++n2)
      Opart[row * HD + n2 * 16 + l15] = __float2bfloat16(o[n2][r] * linv[r]);
  }
  if (quad == 0) ml[rb + l15] = make_float2(m_run, l_run);
}

// ---------------------------------------------------------------------------
// Combine the two KV-split halves (verified R6).
// ---------------------------------------------------------------------------
__global__ __launch_bounds__(256)
void attn_combine(const __hip_bfloat16* __restrict__ Opart,
                  const float2* __restrict__ ml,
                  __hip_bfloat16* __restrict__ out) {
  const int h  = blockIdx.y;
  const int q  = blockIdx.x * 16 + (threadIdx.x >> 4);
  const int d8 = (threadIdx.x & 15) * 8;
  const size_t i0 = (size_t)h * L_SEQ + q;
  const size_t i1 = (size_t)(NH + h) * L_SEQ + q;
  float2 a = ml[i0], b = ml[i1];
  float M  = fmaxf(a.x, b.x);
  float w1 = __expf(a.x - M) * a.y;
  float w2 = __expf(b.x - M) * b.y;
  float inv = 1.f / (w1 + w2);
  w1 *= inv; w2 *= inv;
  short8 o1 = *(const short8*)&Opart[i0 * HD + d8];
  short8 o2 = *(const short8*)&Opart[i1 * HD + d8];
  short8 r;
#pragma unroll
  for (int j = 0; j < 8; ++j)
    r[j] = bf16bits(w1 * bits2f(o1[j]) + w2 * bits2f(o2[j]));
  *(short8*)&out[(size_t)q * DIM + h * HD + d8] = r;
}

// ---------------------------------------------------------------------------
extern "C" void kernel_launch(void* const* d_in, const int* in_sizes, int n_in,
                              void* d_out, int out_size, void* d_ws, size_t ws_size,
                              hipStream_t stream) {
  const float* x       = (const float*)d_in[0];
  const float* pe      = (const float*)d_in[1];
  const float* qkv_w   = (const float*)d_in[2];
  const float* q_scale = (const float*)d_in[3];
  const float* k_scale = (const float*)d_in[4];
  const float* proj_w  = (const float*)d_in[5];
  const float* proj_b  = (const float*)d_in[6];
  float* out = (float*)d_out;

  // Workspace layout (67,108,864 B), phase-disjoint reuse:
  //  phase 1 (cast+gemm):   xb [0,8.4M) | wb [8.4,33.6M) | Cq [33.6,58.8M) | pwb [58.8,67.1M)
  //  phase 2 (epilogue):    reads Cq; writes Qb [0,8.4M) Kb [8.4,16.8M) Vt [16.8,25.2M)
  //  phase 3 (attn):        Opart [33.6,50.3M) ml [50.3,50.9M) attn_out [25.2,33.6M)
  char* base = (char*)d_ws;
  __hip_bfloat16* xb       = (__hip_bfloat16*)base;
  __hip_bfloat16* wb       = (__hip_bfloat16*)(base + 8388608);
  __hip_bfloat16* Cq       = (__hip_bfloat16*)(base + 33554432);
  __hip_bfloat16* pwb      = (__hip_bfloat16*)(base + 58720256);
  __hip_bfloat16* Qb       = (__hip_bfloat16*)base;
  __hip_bfloat16* Kb       = (__hip_bfloat16*)(base + 8388608);
  __hip_bfloat16* Vt       = (__hip_bfloat16*)(base + 16777216);
  __hip_bfloat16* Opart    = (__hip_bfloat16*)(base + 33554432);
  float2*         ml       = (float2*)(base + 50331648);
  __hip_bfloat16* attn_out = (__hip_bfloat16*)(base + 25165824);

  static bool attr_done = false;
  if (!attr_done) {
    hipFuncSetAttribute((const void*)gemm_qkv_256,
                        hipFuncAttributeMaxDynamicSharedMemorySize, 131072);
    attr_done = true;
  }

  cast2_bf16<<<dim3((DIM * DIM + TDIM * DIM) / (256 * 8)), 256, 0, stream>>>(
      x, xb, qkv_w, wb);

  gemm_qkv_256<<<dim3((TDIM / 256) * (L_SEQ / 256)), 512, 131072, stream>>>(xb, wb, Cq);

  qkv_epilogue<<<dim3(1024), 256, 0, stream>>>(Cq, q_scale, k_scale, pe, Qb, Kb, Vt);

  cast_bf16<<<dim3(DIM * DIM / (256 * 8)), 256, 0, stream>>>(proj_w, pwb, DIM * DIM);

  attn_mfma<<<dim3(L_SEQ / 64, NH, 2), 256, 0, stream>>>(Qb, Kb, Vt, Opart, ml);
  attn_combine<<<dim3(L_SEQ / 16, NH), 256, 0, stream>>>(Opart, ml, attn_out);

  gemm_proj<<<dim3(DIM / 128, DIM / 128), 256, 0, stream>>>(
      attn_out, pwb, proj_b, out, L_SEQ, DIM, DIM);
}

// Round 2
// 329.340 us; speedup vs baseline: 1.0362x; 1.0004x over previous
//
#include <hip/hip_runtime.h>
#include <hip/hip_bf16.h>
#include <math.h>

#define L_SEQ 2048
#define DIM   2048
#define NH    16
#define HD    128
#define TDIM  6144

typedef __attribute__((ext_vector_type(8))) short short8;
typedef __attribute__((ext_vector_type(4))) float f32x4;
typedef __attribute__((ext_vector_type(4))) unsigned int u32x4;

// async global->LDS, 16 B per lane. LDS dest = wave-uniform base + lane*16.
__device__ __forceinline__ void gl_lds16(const void* g, void* l) {
  __builtin_amdgcn_global_load_lds(
      (const __attribute__((address_space(1))) unsigned int*)g,
      (__attribute__((address_space(3))) unsigned int*)l, 16, 0, 0);
}

__device__ __forceinline__ short bf16bits(float x) {
  __hip_bfloat16 h = __float2bfloat16(x);
  return *(short*)&h;
}

__device__ __forceinline__ float bits2f(short s) {
  unsigned int u = ((unsigned int)(unsigned short)s) << 16;
  return __uint_as_float(u);
}

__device__ __forceinline__ unsigned int pack_bf16(float a, float b) {
  __hip_bfloat162 h = __float22bfloat162_rn(make_float2(a, b));
  return *(unsigned int*)&h;
}

// ---------------------------------------------------------------------------
// fused fp32 -> bf16 cast of x (4M elems) then qkv_w (12M elems).
// ---------------------------------------------------------------------------
__global__ __launch_bounds__(256)
void cast2_bf16(const float* __restrict__ a, __hip_bfloat16* __restrict__ oa,
                const float* __restrict__ b, __hip_bfloat16* __restrict__ ob) {
  int i = (blockIdx.x * 256 + threadIdx.x) * 8;
  const float* src;
  __hip_bfloat16* dst;
  int off;
  if (i < DIM * DIM) { src = a; dst = oa; off = i; }
  else               { src = b; dst = ob; off = i - DIM * DIM; }
  float4 v0 = *(const float4*)(src + off);
  float4 v1 = *(const float4*)(src + off + 4);
  short8 o;
  o[0] = bf16bits(v0.x); o[1] = bf16bits(v0.y); o[2] = bf16bits(v0.z); o[3] = bf16bits(v0.w);
  o[4] = bf16bits(v1.x); o[5] = bf16bits(v1.y); o[6] = bf16bits(v1.z); o[7] = bf16bits(v1.w);
  *(short8*)(dst + off) = o;
}

__global__ __launch_bounds__(256)
void cast_bf16(const float* __restrict__ in, __hip_bfloat16* __restrict__ out, int n) {
  int i = (blockIdx.x * 256 + threadIdx.x) * 8;
  if (i >= n) return;
  float4 a = *(const float4*)(in + i);
  float4 b = *(const float4*)(in + i + 4);
  short8 o;
  o[0] = bf16bits(a.x); o[1] = bf16bits(a.y); o[2] = bf16bits(a.z); o[3] = bf16bits(a.w);
  o[4] = bf16bits(b.x); o[5] = bf16bits(b.y); o[6] = bf16bits(b.z); o[7] = bf16bits(b.w);
  *(short8*)(out + i) = o;
}

// ---------------------------------------------------------------------------
// QKV GEMM, deep-pipelined 256x256 tile (T3+T4+T5). Verified R1.
// ---------------------------------------------------------------------------
#define QKV_N 6144
#define QKV_K 2048

__global__ __launch_bounds__(512, 2)
void gemm_qkv_256(const __hip_bfloat16* __restrict__ A,
                  const __hip_bfloat16* __restrict__ B,
                  __hip_bfloat16* __restrict__ C) {
  extern __shared__ char smem[];
  const int tid  = threadIdx.x;
  const int lane = tid & 63, w = tid >> 6;
  const int l15  = lane & 15, quad = lane >> 4;
  const int wm   = w >> 2, wn = w & 3;

  const int orig = blockIdx.x;
  const int by = orig & 7;    // M-tile: 8 tiles of 256
  const int bx = orig >> 3;   // N-tile: 24 tiles of 256
  const int m0 = by * 256, n0 = bx * 256;

  const int ar0 = tid >> 2,         aq0 = tid & 3;
  const int ar1 = (512 + tid) >> 2, aq1 = (512 + tid) & 3;
  const __hip_bfloat16* pA0 = A + (size_t)(m0 + ar0) * QKV_K + aq0 * 8;
  const __hip_bfloat16* pA1 = A + (size_t)(m0 + ar1) * QKV_K + aq1 * 8;
  const __hip_bfloat16* pB0 = B + (size_t)(n0 + ar0) * QKV_K + aq0 * 8;
  const __hip_bfloat16* pB1 = B + (size_t)(n0 + ar1) * QKV_K + aq1 * 8;
  const int dst0 = w * 1024;

  f32x4 acc[8][4];
#pragma unroll
  for (int mi = 0; mi < 8; ++mi)
#pragma unroll
    for (int ni = 0; ni < 4; ++ni) acc[mi][ni] = (f32x4){0.f, 0.f, 0.f, 0.f};

  const int aoff = ((wm * 128 + l15) * 32 + quad * 8) * 2;
  const int boff = ((wn * 64 + l15) * 32 + quad * 8) * 2;

#pragma unroll
  for (int p = 0; p < 3; ++p) {
    char* Sp = smem + p * 32768;
    gl_lds16(pA0 + p * 32, Sp + dst0);
    gl_lds16(pA1 + p * 32, Sp + dst0 + 8192);
    gl_lds16(pB0 + p * 32, Sp + 16384 + dst0);
    gl_lds16(pB1 + p * 32, Sp + 16384 + dst0 + 8192);
  }
  asm volatile("s_waitcnt vmcnt(8)\n\ts_barrier" ::: "memory");

  for (int tb = 0; tb < 64; tb += 4) {
#pragma unroll
    for (int u = 0; u < 4; ++u) {
      const int t  = tb + u;
      const char* As = smem + u * 32768;
      const char* Bs = As + 16384;
      const int tn = (t + 3) & 63;
      char* Sn = smem + ((u + 3) & 3) * 32768;

      short8 a[8];
#pragma unroll
      for (int mi = 0; mi < 8; ++mi)
        a[mi] = *(const short8*)(As + aoff + mi * 1024);
      short8 b0 = *(const short8*)(Bs + boff);
      short8 b1 = *(const short8*)(Bs + boff + 1024);
      gl_lds16(pA0 + tn * 32, Sn + dst0);
      gl_lds16(pA1 + tn * 32, Sn + dst0 + 8192);
      __builtin_amdgcn_s_barrier();
      __builtin_amdgcn_s_setprio(1);
#pragma unroll
      for (int mi = 0; mi < 8; ++mi) {
        acc[mi][0] = __builtin_amdgcn_mfma_f32_16x16x32_bf16(a[mi], b0, acc[mi][0], 0, 0, 0);
        acc[mi][1] = __builtin_amdgcn_mfma_f32_16x16x32_bf16(a[mi], b1, acc[mi][1], 0, 0, 0);
      }
      __builtin_amdgcn_s_setprio(0);
      __builtin_amdgcn_s_barrier();

      short8 b2 = *(const short8*)(Bs + boff + 2048);
      short8 b3 = *(const short8*)(Bs + boff + 3072);
      gl_lds16(pB0 + tn * 32, Sn + 16384 + dst0);
      gl_lds16(pB1 + tn * 32, Sn + 16384 + dst0 + 8192);
      asm volatile("s_waitcnt vmcnt(8)\n\ts_barrier" ::: "memory");
      __builtin_amdgcn_s_setprio(1);
#pragma unroll
      for (int mi = 0; mi < 8; ++mi) {
        acc[mi][2] = __builtin_amdgcn_mfma_f32_16x16x32_bf16(a[mi], b2, acc[mi][2], 0, 0, 0);
        acc[mi][3] = __builtin_amdgcn_mfma_f32_16x16x32_bf16(a[mi], b3, acc[mi][3], 0, 0, 0);
      }
      __builtin_amdgcn_s_setprio(0);
      __builtin_amdgcn_s_barrier();
    }
  }

  const int crow = m0 + wm * 128 + quad * 4;
  const int ccol = n0 + wn * 64 + l15;
#pragma unroll
  for (int mi = 0; mi < 8; ++mi)
#pragma unroll
    for (int ni = 0; ni < 4; ++ni)
#pragma unroll
      for (int r = 0; r < 4; ++r)
        C[(size_t)(crow + mi * 16 + r) * QKV_N + ccol + ni * 16] =
            __float2bfloat16(acc[mi][ni][r]);
}

// ---------------------------------------------------------------------------
// Epilogue: reads C[2048][6144] bf16 (L3-resident). Verified R1.
// ---------------------------------------------------------------------------
__global__ __launch_bounds__(256)
void qkv_epilogue(const __hip_bfloat16* __restrict__ C,
                  const float* __restrict__ q_scale, const float* __restrict__ k_scale,
                  const float* __restrict__ pe,
                  __hip_bfloat16* __restrict__ Qb, __hip_bfloat16* __restrict__ Kb,
                  __hip_bfloat16* __restrict__ Vt) {
  const int bid = blockIdx.x;
  const int t = threadIdx.x;
  if (bid < 512) {
    const int sec = bid >> 8;          // 0 = q, 1 = k
    const int h   = (bid >> 4) & 15;
    const int rb  = bid & 15;          // 16 row-blocks of 128
    const float* scale = sec ? k_scale : q_scale;
    const float qmul = sec ? 1.0f : 0.08838834764831845f;
    __hip_bfloat16* dst = sec ? Kb : Qb;

    const int row = t >> 1, half = t & 1;
    const int l = rb * 128 + row;
    const __hip_bfloat16* grow = C + (size_t)l * TDIM + sec * DIM + h * HD + half * 64;

    float ss = 0.f;
#pragma unroll
    for (int c8 = 0; c8 < 64; c8 += 8) {
      short8 v8 = *(const short8*)(grow + c8);
#pragma unroll
      for (int j = 0; j < 8; ++j) { float f = bits2f(v8[j]); ss += f * f; }
    }
    ss += __shfl_xor(ss, 1);
    const float rrms = rsqrtf(ss * (1.f / 128.f) + 1e-6f);

    const float* perow = pe + (size_t)l * 256 + half * 128;
    __hip_bfloat16* drow = dst + ((size_t)h * L_SEQ + l) * HD + half * 64;

#pragma unroll
    for (int c8 = 0; c8 < 64; c8 += 8) {
      short8 v8 = *(const short8*)(grow + c8);
      float f[8];
#pragma unroll
      for (int j = 0; j < 8; ++j)
        f[j] = bits2f(v8[j]) * rrms * scale[half * 64 + c8 + j];
      short8 o;
#pragma unroll
      for (int p = 0; p < 4; ++p) {
        float4 pp = *(const float4*)(perow + c8 * 2 + p * 4);
        float e = f[2 * p], od = f[2 * p + 1];
        o[2 * p]     = bf16bits((pp.x * e + pp.y * od) * qmul);
        o[2 * p + 1] = bf16bits((pp.z * e + pp.w * od) * qmul);
      }
      *(short8*)(drow + c8) = o;
    }
  } else {
    __shared__ short Tt[128 * 72];
    const int vb = bid - 512;
    const int h = vb >> 5, lb = vb & 31;
    const int l0 = lb * 64;
#pragma unroll
    for (int k = 0; k < 4; ++k) {
      int idx = t + k * 256;
      int row = idx >> 4, c = idx & 15;
      short8 v = *(const short8*)(C + (size_t)(l0 + row) * TDIM + 2 * DIM + h * HD + c * 8);
#pragma unroll
      for (int j = 0; j < 8; ++j) Tt[(c * 8 + j) * 72 + row] = v[j];
    }
    __syncthreads();
    const int d = t >> 1, lh = t & 1;
    __hip_bfloat16* vrow = Vt + ((size_t)h * HD + d) * L_SEQ + l0 + lh * 32;
#pragma unroll
    for (int k = 0; k < 4; ++k) {
      short8 o = *(const short8*)&Tt[d * 72 + lh * 32 + k * 8];
      *(short8*)(vrow + k * 8) = o;
    }
  }
}

// ---------------------------------------------------------------------------
// bf16 MFMA GEMM (m97 structure) — proj only (fp32 out + bias). Verified.
// ---------------------------------------------------------------------------
__global__ __launch_bounds__(256)
void gemm_proj(const __hip_bfloat16* __restrict__ A, const __hip_bfloat16* __restrict__ B,
               const float* __restrict__ bias, float* __restrict__ C,
               int M, int N, int K) {
  const int n0 = blockIdx.x * 128, m0 = blockIdx.y * 128;
  const int t = threadIdx.x, lane = t & 63, w = t >> 6;
  const int l15 = lane & 15, quad = lane >> 4;
  const int wm = (w & 1) * 64, wn = (w >> 1) * 64;

  __shared__ __align__(16) __hip_bfloat16 As[128 * 32];
  __shared__ __align__(16) __hip_bfloat16 Bs[128 * 32];

  f32x4 acc[4][4];
#pragma unroll
  for (int mt = 0; mt < 4; ++mt)
#pragma unroll
    for (int nt = 0; nt < 4; ++nt) acc[mt][nt] = (f32x4){0.f, 0.f, 0.f, 0.f};

  const int arow  = lane >> 2;
  const int acol8 = (lane & 3) * 8;
  const __hip_bfloat16* Ab = A + (size_t)(m0 + w * 16 + arow) * K + acol8;
  const __hip_bfloat16* Bb = B + (size_t)(n0 + w * 16 + arow) * K + acol8;
  __hip_bfloat16* As_base = As + (size_t)(w * 16) * 32;
  __hip_bfloat16* Bs_base = Bs + (size_t)(w * 16) * 32;

  for (int kb = 0; kb < K; kb += 32) {
    gl_lds16(Ab + kb,                As_base);
    gl_lds16(Ab + kb + (size_t)64*K, As_base + 64 * 32);
    gl_lds16(Bb + kb,                Bs_base);
    gl_lds16(Bb + kb + (size_t)64*K, Bs_base + 64 * 32);
    __syncthreads();

    short8 am[4], bn[4];
#pragma unroll
    for (int mt = 0; mt < 4; ++mt)
      am[mt] = *(const short8*)&As[(size_t)(wm + mt*16 + l15) * 32 + quad * 8];
#pragma unroll
    for (int nt = 0; nt < 4; ++nt)
      bn[nt] = *(const short8*)&Bs[(size_t)(wn + nt*16 + l15) * 32 + quad * 8];
#pragma unroll
    for (int mt = 0; mt < 4; ++mt)
#pragma unroll
      for (int nt = 0; nt < 4; ++nt)
        acc[mt][nt] = __builtin_amdgcn_mfma_f32_16x16x32_bf16(am[mt], bn[nt], acc[mt][nt], 0, 0, 0);
    __syncthreads();
  }

#pragma unroll
  for (int mt = 0; mt < 4; ++mt)
#pragma unroll
    for (int nt = 0; nt < 4; ++nt) {
      int col = n0 + wn + nt * 16 + l15;
#pragma unroll
      for (int r = 0; r < 4; ++r) {
        int row = m0 + wm + mt * 16 + quad * 4 + r;
        C[(size_t)row * N + col] = acc[mt][nt][r] + bias[col];
      }
    }
}

// ---------------------------------------------------------------------------
// Flash attention v2: full KV sweep per block (no z-split), double-buffered
// K/V LDS with 2-deep async pipeline (stage t+1 before compute t; single
// fused vmcnt(0)+barrier after compute). Writes normalized attn_out directly.
// 512 blocks = 2 blocks/CU at 64 KB LDS. XCD swizzle: each XCD owns 2 heads.
// ---------------------------------------------------------------------------
__global__ __launch_bounds__(256, 2)
void attn_mfma(const __hip_bfloat16* __restrict__ Qb,
               const __hip_bfloat16* __restrict__ Kb,
               const __hip_bfloat16* __restrict__ Vt,
               __hip_bfloat16* __restrict__ out) {
  const int orig = blockIdx.x;                     // 512 blocks, 512 % 8 == 0
  const int wg   = (orig & 7) * 64 + (orig >> 3);  // bijective XCD swizzle
  const int h    = wg >> 5;
  const int q0   = (wg & 31) * 64;
  const int t  = threadIdx.x;
  const int lane = t & 63, w = t >> 6;
  const int l15 = lane & 15, quad = lane >> 4;
  const int sw = l15 & 7;

  __shared__ __align__(16) __hip_bfloat16 Ks[2][64 * 128];
  __shared__ __align__(16) __hip_bfloat16 Vs[2][128 * 64];

  const __hip_bfloat16* kbase = Kb + (size_t)h * L_SEQ * HD;
  const __hip_bfloat16* vbase = Vt + (size_t)h * HD * L_SEQ;

  auto STAGE = [&](int kt_, int b_) {
    const int k0_ = kt_ * 64;
#pragma unroll
    for (int i = 0; i < 4; ++i) {
      int krow = w * 16 + i * 4 + (lane >> 4);
      int kch  = (lane & 15) ^ (krow & 7);
      gl_lds16(kbase + (size_t)(k0_ + krow) * HD + kch * 8,
               &Ks[b_][(w * 16 + i * 4) * 128]);
    }
#pragma unroll
    for (int i = 0; i < 4; ++i) {
      int vrow = w * 32 + i * 8 + (lane >> 3);
      int vch  = (lane & 7) ^ (vrow & 7);
      gl_lds16(vbase + (size_t)vrow * L_SEQ + k0_ + vch * 8,
               &Vs[b_][(w * 32 + i * 8) * 64]);
    }
  };

  short8 aq[4];
  {
    const __hip_bfloat16* qbase = Qb + ((size_t)h * L_SEQ + q0 + w * 16 + l15) * HD;
#pragma unroll
    for (int ks = 0; ks < 4; ++ks)
      aq[ks] = *(const short8*)(qbase + ks * 32 + quad * 8);
  }

  f32x4 o[8];
#pragma unroll
  for (int n2 = 0; n2 < 8; ++n2) o[n2] = (f32x4){0.f, 0.f, 0.f, 0.f};
  float m_run = -1e30f, l_run = 0.f;

  STAGE(0, 0);
  asm volatile("s_waitcnt vmcnt(0)\n\ts_barrier" ::: "memory");

  for (int kt = 0; kt < 32; ++kt) {
    const int buf = kt & 1;
    if (kt < 31) STAGE(kt + 1, buf ^ 1);   // loads in flight across compute

    f32x4 s[4];
#pragma unroll
    for (int nt = 0; nt < 4; ++nt) s[nt] = (f32x4){0.f, 0.f, 0.f, 0.f};
    __builtin_amdgcn_s_setprio(1);
#pragma unroll
    for (int ks = 0; ks < 4; ++ks) {
      short8 bk[4];
#pragma unroll
      for (int nt = 0; nt < 4; ++nt)
        bk[nt] = *(const short8*)&Ks[buf][(nt * 16 + l15) * 128 + ((ks * 4 + quad) ^ sw) * 8];
#pragma unroll
      for (int nt = 0; nt < 4; ++nt)
        s[nt] = __builtin_amdgcn_mfma_f32_16x16x32_bf16(bk[nt], aq[ks], s[nt], 0, 0, 0);
    }
    __builtin_amdgcn_s_setprio(0);

    float mx0 = fmaxf(fmaxf(s[0][0], s[0][1]), fmaxf(s[0][2], s[0][3]));
    float mx1 = fmaxf(fmaxf(s[1][0], s[1][1]), fmaxf(s[1][2], s[1][3]));
    float mx2 = fmaxf(fmaxf(s[2][0], s[2][1]), fmaxf(s[2][2], s[2][3]));
    float mx3 = fmaxf(fmaxf(s[3][0], s[3][1]), fmaxf(s[3][2], s[3][3]));
    float rm = fmaxf(fmaxf(mx0, mx1), fmaxf(mx2, mx3));
    rm = fmaxf(rm, __shfl_xor(rm, 16));
    rm = fmaxf(rm, __shfl_xor(rm, 32));
    float mnew = fmaxf(m_run, rm);
    float alpha = __expf(m_run - mnew);
    m_run = mnew;

    float sum = 0.f;
#pragma unroll
    for (int nt = 0; nt < 4; ++nt)
#pragma unroll
      for (int r = 0; r < 4; ++r) {
        float p = __expf(s[nt][r] - mnew);
        s[nt][r] = p;
        sum += p;
      }
    sum += __shfl_xor(sum, 16);
    sum += __shfl_xor(sum, 32);
    l_run = l_run * alpha + sum;

    float alpha_r[4];
#pragma unroll
    for (int r = 0; r < 4; ++r) alpha_r[r] = __shfl(alpha, quad * 4 + r);
#pragma unroll
    for (int n2 = 0; n2 < 8; ++n2)
#pragma unroll
      for (int r = 0; r < 4; ++r) o[n2][r] *= alpha_r[r];

    unsigned int pk[4][2];
#pragma unroll
    for (int nt = 0; nt < 4; ++nt) {
      pk[nt][0] = pack_bf16(s[nt][0], s[nt][1]);
      pk[nt][1] = pack_bf16(s[nt][2], s[nt][3]);
    }
    short8 ap[2];
#pragma unroll
    for (int ks2 = 0; ks2 < 2; ++ks2) {
      u32x4 a32;
#pragma unroll
      for (int jp = 0; jp < 4; ++jp) {
        int quad_src = (quad & 1) * 2 + (jp >> 1);
        int src = (quad_src << 4) | l15;
        int rp = jp & 1;
        unsigned int v0 = __shfl((int)pk[2 * ks2 + 0][rp], src);
        unsigned int v1 = __shfl((int)pk[2 * ks2 + 1][rp], src);
        a32[jp] = (quad >> 1) ? v1 : v0;
      }
      ap[ks2] = *(short8*)&a32;
    }

    __builtin_amdgcn_s_setprio(1);
#pragma unroll
    for (int ks2 = 0; ks2 < 2; ++ks2)
#pragma unroll
      for (int n2 = 0; n2 < 8; ++n2) {
        short8 bv = *(const short8*)&Vs[buf][(n2 * 16 + l15) * 64 + ((ks2 * 4 + quad) ^ sw) * 8];
        o[n2] = __builtin_amdgcn_mfma_f32_16x16x32_bf16(ap[ks2], bv, o[n2], 0, 0, 0);
      }
    __builtin_amdgcn_s_setprio(0);

    // loads for tile kt+1 had the whole compute phase to land; cheap drain.
    asm volatile("s_waitcnt vmcnt(0)\n\ts_barrier" ::: "memory");
  }

  float linv[4];
#pragma unroll
  for (int r = 0; r < 4; ++r) linv[r] = 1.f / __shfl(l_run, quad * 4 + r);
#pragma unroll
  for (int r = 0; r < 4; ++r) {
    int row = q0 + w * 16 + quad * 4 + r;
#pragma unroll
    for (int n2 = 0; n2 < 8; ++n2)
      out[(size_t)row * DIM + h * HD + n2 * 16 + l15] =
          __float2bfloat16(o[n2][r] * linv[r]);
  }
}

// ---------------------------------------------------------------------------
extern "C" void kernel_launch(void* const* d_in, const int* in_sizes, int n_in,
                              void* d_out, int out_size, void* d_ws, size_t ws_size,
                              hipStream_t stream) {
  const float* x       = (const float*)d_in[0];
  const float* pe      = (const float*)d_in[1];
  const float* qkv_w   = (const float*)d_in[2];
  const float* q_scale = (const float*)d_in[3];
  const float* k_scale = (const float*)d_in[4];
  const float* proj_w  = (const float*)d_in[5];
  const float* proj_b  = (const float*)d_in[6];
  float* out = (float*)d_out;

  // Workspace layout (67,108,864 B), phase-disjoint reuse:
  //  phase 1 (cast+gemm):   xb [0,8.4M) | wb [8.4,33.6M) | Cq [33.6,58.8M) | pwb [58.8,67.1M)
  //  phase 2 (epilogue):    reads Cq; writes Qb [0,8.4M) Kb [8.4,16.8M) Vt [16.8,25.2M)
  //  phase 3 (attn):        reads Qb/Kb/Vt; writes attn_out [25.2,33.6M)
  char* base = (char*)d_ws;
  __hip_bfloat16* xb       = (__hip_bfloat16*)base;
  __hip_bfloat16* wb       = (__hip_bfloat16*)(base + 8388608);
  __hip_bfloat16* Cq       = (__hip_bfloat16*)(base + 33554432);
  __hip_bfloat16* pwb      = (__hip_bfloat16*)(base + 58720256);
  __hip_bfloat16* Qb       = (__hip_bfloat16*)base;
  __hip_bfloat16* Kb       = (__hip_bfloat16*)(base + 8388608);
  __hip_bfloat16* Vt       = (__hip_bfloat16*)(base + 16777216);
  __hip_bfloat16* attn_out = (__hip_bfloat16*)(base + 25165824);

  static bool attr_done = false;
  if (!attr_done) {
    hipFuncSetAttribute((const void*)gemm_qkv_256,
                        hipFuncAttributeMaxDynamicSharedMemorySize, 131072);
    attr_done = true;
  }

  cast2_bf16<<<dim3((DIM * DIM + TDIM * DIM) / (256 * 8)), 256, 0, stream>>>(
      x, xb, qkv_w, wb);

  gemm_qkv_256<<<dim3((TDIM / 256) * (L_SEQ / 256)), 512, 131072, stream>>>(xb, wb, Cq);

  qkv_epilogue<<<dim3(1024), 256, 0, stream>>>(Cq, q_scale, k_scale, pe, Qb, Kb, Vt);

  cast_bf16<<<dim3(DIM * DIM / (256 * 8)), 256, 0, stream>>>(proj_w, pwb, DIM * DIM);

  attn_mfma<<<dim3(512), 256, 0, stream>>>(Qb, Kb, Vt, attn_out);

  gemm_proj<<<dim3(DIM / 128, DIM / 128), 256, 0, stream>>>(
      attn_out, pwb, proj_b, out, L_SEQ, DIM, DIM);
}

// Round 3
// 329.071 us; speedup vs baseline: 1.0371x; 1.0008x over previous
//
#include <hip/hip_runtime.h>
#include <hip/hip_bf16.h>
#include <math.h>

#define L_SEQ 2048
#define DIM   2048
#define NH    16
#define HD    128
#define TDIM  6144

typedef __attribute__((ext_vector_type(8))) short short8;
typedef __attribute__((ext_vector_type(4))) float f32x4;
typedef __attribute__((ext_vector_type(4))) unsigned int u32x4;

// async global->LDS, 16 B per lane. LDS dest = wave-uniform base + lane*16.
__device__ __forceinline__ void gl_lds16(const void* g, void* l) {
  __builtin_amdgcn_global_load_lds(
      (const __attribute__((address_space(1))) unsigned int*)g,
      (__attribute__((address_space(3))) unsigned int*)l, 16, 0, 0);
}

__device__ __forceinline__ short bf16bits(float x) {
  __hip_bfloat16 h = __float2bfloat16(x);
  return *(short*)&h;
}

__device__ __forceinline__ float bits2f(short s) {
  unsigned int u = ((unsigned int)(unsigned short)s) << 16;
  return __uint_as_float(u);
}

__device__ __forceinline__ unsigned int pack_bf16(float a, float b) {
  __hip_bfloat162 h = __float22bfloat162_rn(make_float2(a, b));
  return *(unsigned int*)&h;
}

// ---------------------------------------------------------------------------
// fused fp32 -> bf16 cast of x (4M elems) then qkv_w (12M elems).
// ---------------------------------------------------------------------------
__global__ __launch_bounds__(256)
void cast2_bf16(const float* __restrict__ a, __hip_bfloat16* __restrict__ oa,
                const float* __restrict__ b, __hip_bfloat16* __restrict__ ob) {
  int i = (blockIdx.x * 256 + threadIdx.x) * 8;
  const float* src;
  __hip_bfloat16* dst;
  int off;
  if (i < DIM * DIM) { src = a; dst = oa; off = i; }
  else               { src = b; dst = ob; off = i - DIM * DIM; }
  float4 v0 = *(const float4*)(src + off);
  float4 v1 = *(const float4*)(src + off + 4);
  short8 o;
  o[0] = bf16bits(v0.x); o[1] = bf16bits(v0.y); o[2] = bf16bits(v0.z); o[3] = bf16bits(v0.w);
  o[4] = bf16bits(v1.x); o[5] = bf16bits(v1.y); o[6] = bf16bits(v1.z); o[7] = bf16bits(v1.w);
  *(short8*)(dst + off) = o;
}

__global__ __launch_bounds__(256)
void cast_bf16(const float* __restrict__ in, __hip_bfloat16* __restrict__ out, int n) {
  int i = (blockIdx.x * 256 + threadIdx.x) * 8;
  if (i >= n) return;
  float4 a = *(const float4*)(in + i);
  float4 b = *(const float4*)(in + i + 4);
  short8 o;
  o[0] = bf16bits(a.x); o[1] = bf16bits(a.y); o[2] = bf16bits(a.z); o[3] = bf16bits(a.w);
  o[4] = bf16bits(b.x); o[5] = bf16bits(b.y); o[6] = bf16bits(b.z); o[7] = bf16bits(b.w);
  *(short8*)(out + i) = o;
}

// ---------------------------------------------------------------------------
// QKV GEMM, deep-pipelined 256x256 tile (T3+T4+T5). Verified R1.
// ---------------------------------------------------------------------------
#define QKV_N 6144
#define QKV_K 2048

__global__ __launch_bounds__(512, 2)
void gemm_qkv_256(const __hip_bfloat16* __restrict__ A,
                  const __hip_bfloat16* __restrict__ B,
                  __hip_bfloat16* __restrict__ C) {
  extern __shared__ char smem[];
  const int tid  = threadIdx.x;
  const int lane = tid & 63, w = tid >> 6;
  const int l15  = lane & 15, quad = lane >> 4;
  const int wm   = w >> 2, wn = w & 3;

  const int orig = blockIdx.x;
  const int by = orig & 7;    // M-tile: 8 tiles of 256
  const int bx = orig >> 3;   // N-tile: 24 tiles of 256
  const int m0 = by * 256, n0 = bx * 256;

  const int ar0 = tid >> 2,         aq0 = tid & 3;
  const int ar1 = (512 + tid) >> 2, aq1 = (512 + tid) & 3;
  const __hip_bfloat16* pA0 = A + (size_t)(m0 + ar0) * QKV_K + aq0 * 8;
  const __hip_bfloat16* pA1 = A + (size_t)(m0 + ar1) * QKV_K + aq1 * 8;
  const __hip_bfloat16* pB0 = B + (size_t)(n0 + ar0) * QKV_K + aq0 * 8;
  const __hip_bfloat16* pB1 = B + (size_t)(n0 + ar1) * QKV_K + aq1 * 8;
  const int dst0 = w * 1024;

  f32x4 acc[8][4];
#pragma unroll
  for (int mi = 0; mi < 8; ++mi)
#pragma unroll
    for (int ni = 0; ni < 4; ++ni) acc[mi][ni] = (f32x4){0.f, 0.f, 0.f, 0.f};

  const int aoff = ((wm * 128 + l15) * 32 + quad * 8) * 2;
  const int boff = ((wn * 64 + l15) * 32 + quad * 8) * 2;

#pragma unroll
  for (int p = 0; p < 3; ++p) {
    char* Sp = smem + p * 32768;
    gl_lds16(pA0 + p * 32, Sp + dst0);
    gl_lds16(pA1 + p * 32, Sp + dst0 + 8192);
    gl_lds16(pB0 + p * 32, Sp + 16384 + dst0);
    gl_lds16(pB1 + p * 32, Sp + 16384 + dst0 + 8192);
  }
  asm volatile("s_waitcnt vmcnt(8)\n\ts_barrier" ::: "memory");

  for (int tb = 0; tb < 64; tb += 4) {
#pragma unroll
    for (int u = 0; u < 4; ++u) {
      const int t  = tb + u;
      const char* As = smem + u * 32768;
      const char* Bs = As + 16384;
      const int tn = (t + 3) & 63;
      char* Sn = smem + ((u + 3) & 3) * 32768;

      short8 a[8];
#pragma unroll
      for (int mi = 0; mi < 8; ++mi)
        a[mi] = *(const short8*)(As + aoff + mi * 1024);
      short8 b0 = *(const short8*)(Bs + boff);
      short8 b1 = *(const short8*)(Bs + boff + 1024);
      gl_lds16(pA0 + tn * 32, Sn + dst0);
      gl_lds16(pA1 + tn * 32, Sn + dst0 + 8192);
      __builtin_amdgcn_s_barrier();
      __builtin_amdgcn_s_setprio(1);
#pragma unroll
      for (int mi = 0; mi < 8; ++mi) {
        acc[mi][0] = __builtin_amdgcn_mfma_f32_16x16x32_bf16(a[mi], b0, acc[mi][0], 0, 0, 0);
        acc[mi][1] = __builtin_amdgcn_mfma_f32_16x16x32_bf16(a[mi], b1, acc[mi][1], 0, 0, 0);
      }
      __builtin_amdgcn_s_setprio(0);
      __builtin_amdgcn_s_barrier();

      short8 b2 = *(const short8*)(Bs + boff + 2048);
      short8 b3 = *(const short8*)(Bs + boff + 3072);
      gl_lds16(pB0 + tn * 32, Sn + 16384 + dst0);
      gl_lds16(pB1 + tn * 32, Sn + 16384 + dst0 + 8192);
      asm volatile("s_waitcnt vmcnt(8)\n\ts_barrier" ::: "memory");
      __builtin_amdgcn_s_setprio(1);
#pragma unroll
      for (int mi = 0; mi < 8; ++mi) {
        acc[mi][2] = __builtin_amdgcn_mfma_f32_16x16x32_bf16(a[mi], b2, acc[mi][2], 0, 0, 0);
        acc[mi][3] = __builtin_amdgcn_mfma_f32_16x16x32_bf16(a[mi], b3, acc[mi][3], 0, 0, 0);
      }
      __builtin_amdgcn_s_setprio(0);
      __builtin_amdgcn_s_barrier();
    }
  }

  const int crow = m0 + wm * 128 + quad * 4;
  const int ccol = n0 + wn * 64 + l15;
#pragma unroll
  for (int mi = 0; mi < 8; ++mi)
#pragma unroll
    for (int ni = 0; ni < 4; ++ni)
#pragma unroll
      for (int r = 0; r < 4; ++r)
        C[(size_t)(crow + mi * 16 + r) * QKV_N + ccol + ni * 16] =
            __float2bfloat16(acc[mi][ni][r]);
}

// ---------------------------------------------------------------------------
// Epilogue: reads C[2048][6144] bf16 (L3-resident). Verified R1.
// ---------------------------------------------------------------------------
__global__ __launch_bounds__(256)
void qkv_epilogue(const __hip_bfloat16* __restrict__ C,
                  const float* __restrict__ q_scale, const float* __restrict__ k_scale,
                  const float* __restrict__ pe,
                  __hip_bfloat16* __restrict__ Qb, __hip_bfloat16* __restrict__ Kb,
                  __hip_bfloat16* __restrict__ Vt) {
  const int bid = blockIdx.x;
  const int t = threadIdx.x;
  if (bid < 512) {
    const int sec = bid >> 8;          // 0 = q, 1 = k
    const int h   = (bid >> 4) & 15;
    const int rb  = bid & 15;          // 16 row-blocks of 128
    const float* scale = sec ? k_scale : q_scale;
    const float qmul = sec ? 1.0f : 0.08838834764831845f;
    __hip_bfloat16* dst = sec ? Kb : Qb;

    const int row = t >> 1, half = t & 1;
    const int l = rb * 128 + row;
    const __hip_bfloat16* grow = C + (size_t)l * TDIM + sec * DIM + h * HD + half * 64;

    float ss = 0.f;
#pragma unroll
    for (int c8 = 0; c8 < 64; c8 += 8) {
      short8 v8 = *(const short8*)(grow + c8);
#pragma unroll
      for (int j = 0; j < 8; ++j) { float f = bits2f(v8[j]); ss += f * f; }
    }
    ss += __shfl_xor(ss, 1);
    const float rrms = rsqrtf(ss * (1.f / 128.f) + 1e-6f);

    const float* perow = pe + (size_t)l * 256 + half * 128;
    __hip_bfloat16* drow = dst + ((size_t)h * L_SEQ + l) * HD + half * 64;

#pragma unroll
    for (int c8 = 0; c8 < 64; c8 += 8) {
      short8 v8 = *(const short8*)(grow + c8);
      float f[8];
#pragma unroll
      for (int j = 0; j < 8; ++j)
        f[j] = bits2f(v8[j]) * rrms * scale[half * 64 + c8 + j];
      short8 o;
#pragma unroll
      for (int p = 0; p < 4; ++p) {
        float4 pp = *(const float4*)(perow + c8 * 2 + p * 4);
        float e = f[2 * p], od = f[2 * p + 1];
        o[2 * p]     = bf16bits((pp.x * e + pp.y * od) * qmul);
        o[2 * p + 1] = bf16bits((pp.z * e + pp.w * od) * qmul);
      }
      *(short8*)(drow + c8) = o;
    }
  } else {
    __shared__ short Tt[128 * 72];
    const int vb = bid - 512;
    const int h = vb >> 5, lb = vb & 31;
    const int l0 = lb * 64;
#pragma unroll
    for (int k = 0; k < 4; ++k) {
      int idx = t + k * 256;
      int row = idx >> 4, c = idx & 15;
      short8 v = *(const short8*)(C + (size_t)(l0 + row) * TDIM + 2 * DIM + h * HD + c * 8);
#pragma unroll
      for (int j = 0; j < 8; ++j) Tt[(c * 8 + j) * 72 + row] = v[j];
    }
    __syncthreads();
    const int d = t >> 1, lh = t & 1;
    __hip_bfloat16* vrow = Vt + ((size_t)h * HD + d) * L_SEQ + l0 + lh * 32;
#pragma unroll
    for (int k = 0; k < 4; ++k) {
      short8 o = *(const short8*)&Tt[d * 72 + lh * 32 + k * 8];
      *(short8*)(vrow + k * 8) = o;
    }
  }
}

// ---------------------------------------------------------------------------
// bf16 MFMA GEMM (m97 structure) — proj only (fp32 out + bias). Verified.
// ---------------------------------------------------------------------------
__global__ __launch_bounds__(256)
void gemm_proj(const __hip_bfloat16* __restrict__ A, const __hip_bfloat16* __restrict__ B,
               const float* __restrict__ bias, float* __restrict__ C,
               int M, int N, int K) {
  const int n0 = blockIdx.x * 128, m0 = blockIdx.y * 128;
  const int t = threadIdx.x, lane = t & 63, w = t >> 6;
  const int l15 = lane & 15, quad = lane >> 4;
  const int wm = (w & 1) * 64, wn = (w >> 1) * 64;

  __shared__ __align__(16) __hip_bfloat16 As[128 * 32];
  __shared__ __align__(16) __hip_bfloat16 Bs[128 * 32];

  f32x4 acc[4][4];
#pragma unroll
  for (int mt = 0; mt < 4; ++mt)
#pragma unroll
    for (int nt = 0; nt < 4; ++nt) acc[mt][nt] = (f32x4){0.f, 0.f, 0.f, 0.f};

  const int arow  = lane >> 2;
  const int acol8 = (lane & 3) * 8;
  const __hip_bfloat16* Ab = A + (size_t)(m0 + w * 16 + arow) * K + acol8;
  const __hip_bfloat16* Bb = B + (size_t)(n0 + w * 16 + arow) * K + acol8;
  __hip_bfloat16* As_base = As + (size_t)(w * 16) * 32;
  __hip_bfloat16* Bs_base = Bs + (size_t)(w * 16) * 32;

  for (int kb = 0; kb < K; kb += 32) {
    gl_lds16(Ab + kb,                As_base);
    gl_lds16(Ab + kb + (size_t)64*K, As_base + 64 * 32);
    gl_lds16(Bb + kb,                Bs_base);
    gl_lds16(Bb + kb + (size_t)64*K, Bs_base + 64 * 32);
    __syncthreads();

    short8 am[4], bn[4];
#pragma unroll
    for (int mt = 0; mt < 4; ++mt)
      am[mt] = *(const short8*)&As[(size_t)(wm + mt*16 + l15) * 32 + quad * 8];
#pragma unroll
    for (int nt = 0; nt < 4; ++nt)
      bn[nt] = *(const short8*)&Bs[(size_t)(wn + nt*16 + l15) * 32 + quad * 8];
#pragma unroll
    for (int mt = 0; mt < 4; ++mt)
#pragma unroll
      for (int nt = 0; nt < 4; ++nt)
        acc[mt][nt] = __builtin_amdgcn_mfma_f32_16x16x32_bf16(am[mt], bn[nt], acc[mt][nt], 0, 0, 0);
    __syncthreads();
  }

#pragma unroll
  for (int mt = 0; mt < 4; ++mt)
#pragma unroll
    for (int nt = 0; nt < 4; ++nt) {
      int col = n0 + wn + nt * 16 + l15;
#pragma unroll
      for (int r = 0; r < 4; ++r) {
        int row = m0 + wm + mt * 16 + quad * 4 + r;
        C[(size_t)row * N + col] = acc[mt][nt][r] + bias[col];
      }
    }
}

// ---------------------------------------------------------------------------
// Flash attention v3: z=4 KV-split for occupancy (2048 blocks, 32 KB LDS ->
// 5 blocks/CU = 20 waves/CU), R1-verified single-buffer tile schedule,
// bijective XCD swizzle (each XCD owns 2 heads), T13 defer-max.
// ---------------------------------------------------------------------------
#define NZ 4
#define ZLEN (L_SEQ / NZ)

__global__ __launch_bounds__(256, 4)
void attn_mfma(const __hip_bfloat16* __restrict__ Qb,
               const __hip_bfloat16* __restrict__ Kb,
               const __hip_bfloat16* __restrict__ Vt,
               __hip_bfloat16* __restrict__ Opart, float2* __restrict__ ml) {
  // 2048 blocks; wg = (orig&7)*256 + orig>>3 is bijective; XCD c -> heads 2c,2c+1
  const int orig = blockIdx.x;
  const int wg   = (orig & 7) * 256 + (orig >> 3);
  const int h    = wg >> 7;
  const int rem  = wg & 127;
  const int z    = rem >> 5;
  const int q0   = (rem & 31) * 64;
  const int t  = threadIdx.x;
  const int lane = t & 63, w = t >> 6;
  const int l15 = lane & 15, quad = lane >> 4;
  const int sw = l15 & 7;

  __shared__ __align__(16) __hip_bfloat16 Ks[64 * 128];
  __shared__ __align__(16) __hip_bfloat16 Vs[128 * 64];

  const __hip_bfloat16* kbase = Kb + (size_t)h * L_SEQ * HD;
  const __hip_bfloat16* vbase = Vt + (size_t)h * HD * L_SEQ;

  short8 aq[4];
  {
    const __hip_bfloat16* qbase = Qb + ((size_t)h * L_SEQ + q0 + w * 16 + l15) * HD;
#pragma unroll
    for (int ks = 0; ks < 4; ++ks)
      aq[ks] = *(const short8*)(qbase + ks * 32 + quad * 8);
  }

  f32x4 o[8];
#pragma unroll
  for (int n2 = 0; n2 < 8; ++n2) o[n2] = (f32x4){0.f, 0.f, 0.f, 0.f};
  float m_run = -1e30f, l_run = 0.f;

  for (int kt = 0; kt < ZLEN / 64; ++kt) {
    const int k0 = z * ZLEN + kt * 64;
#pragma unroll
    for (int i = 0; i < 4; ++i) {
      int krow = w * 16 + i * 4 + (lane >> 4);
      int kch  = (lane & 15) ^ (krow & 7);
      gl_lds16(kbase + (size_t)(k0 + krow) * HD + kch * 8,
               &Ks[(w * 16 + i * 4) * 128]);
    }
#pragma unroll
    for (int i = 0; i < 4; ++i) {
      int vrow = w * 32 + i * 8 + (lane >> 3);
      int vch  = (lane & 7) ^ (vrow & 7);
      gl_lds16(vbase + (size_t)vrow * L_SEQ + k0 + vch * 8,
               &Vs[(w * 32 + i * 8) * 64]);
    }
    __syncthreads();

    f32x4 s[4];
#pragma unroll
    for (int nt = 0; nt < 4; ++nt) s[nt] = (f32x4){0.f, 0.f, 0.f, 0.f};
    __builtin_amdgcn_s_setprio(1);
#pragma unroll
    for (int ks = 0; ks < 4; ++ks) {
      short8 bk[4];
#pragma unroll
      for (int nt = 0; nt < 4; ++nt)
        bk[nt] = *(const short8*)&Ks[(nt * 16 + l15) * 128 + ((ks * 4 + quad) ^ sw) * 8];
#pragma unroll
      for (int nt = 0; nt < 4; ++nt)
        s[nt] = __builtin_amdgcn_mfma_f32_16x16x32_bf16(bk[nt], aq[ks], s[nt], 0, 0, 0);
    }
    __builtin_amdgcn_s_setprio(0);

    float mx0 = fmaxf(fmaxf(s[0][0], s[0][1]), fmaxf(s[0][2], s[0][3]));
    float mx1 = fmaxf(fmaxf(s[1][0], s[1][1]), fmaxf(s[1][2], s[1][3]));
    float mx2 = fmaxf(fmaxf(s[2][0], s[2][1]), fmaxf(s[2][2], s[2][3]));
    float mx3 = fmaxf(fmaxf(s[3][0], s[3][1]), fmaxf(s[3][2], s[3][3]));
    float rm = fmaxf(fmaxf(mx0, mx1), fmaxf(mx2, mx3));
    rm = fmaxf(rm, __shfl_xor(rm, 16));
    rm = fmaxf(rm, __shfl_xor(rm, 32));

    // T13 defer-max: skip the O-rescale while the running max is stable
    // (P bounded by e^8; bf16/f32 accum tolerates). Wave-uniform branch.
    if (!__all(rm <= m_run + 8.f)) {
      float mnew = fmaxf(m_run, rm);
      float alpha = __expf(m_run - mnew);
      m_run = mnew;
      l_run *= alpha;
      float alpha_r[4];
#pragma unroll
      for (int r = 0; r < 4; ++r) alpha_r[r] = __shfl(alpha, quad * 4 + r);
#pragma unroll
      for (int n2 = 0; n2 < 8; ++n2)
#pragma unroll
        for (int r = 0; r < 4; ++r) o[n2][r] *= alpha_r[r];
    }

    float sum = 0.f;
#pragma unroll
    for (int nt = 0; nt < 4; ++nt)
#pragma unroll
      for (int r = 0; r < 4; ++r) {
        float p = __expf(s[nt][r] - m_run);
        s[nt][r] = p;
        sum += p;
      }
    sum += __shfl_xor(sum, 16);
    sum += __shfl_xor(sum, 32);
    l_run += sum;

    unsigned int pk[4][2];
#pragma unroll
    for (int nt = 0; nt < 4; ++nt) {
      pk[nt][0] = pack_bf16(s[nt][0], s[nt][1]);
      pk[nt][1] = pack_bf16(s[nt][2], s[nt][3]);
    }
    short8 ap[2];
#pragma unroll
    for (int ks2 = 0; ks2 < 2; ++ks2) {
      u32x4 a32;
#pragma unroll
      for (int jp = 0; jp < 4; ++jp) {
        int quad_src = (quad & 1) * 2 + (jp >> 1);
        int src = (quad_src << 4) | l15;
        int rp = jp & 1;
        unsigned int v0 = __shfl((int)pk[2 * ks2 + 0][rp], src);
        unsigned int v1 = __shfl((int)pk[2 * ks2 + 1][rp], src);
        a32[jp] = (quad >> 1) ? v1 : v0;
      }
      ap[ks2] = *(short8*)&a32;
    }

    __builtin_amdgcn_s_setprio(1);
#pragma unroll
    for (int ks2 = 0; ks2 < 2; ++ks2)
#pragma unroll
      for (int n2 = 0; n2 < 8; ++n2) {
        short8 bv = *(const short8*)&Vs[(n2 * 16 + l15) * 64 + ((ks2 * 4 + quad) ^ sw) * 8];
        o[n2] = __builtin_amdgcn_mfma_f32_16x16x32_bf16(ap[ks2], bv, o[n2], 0, 0, 0);
      }
    __builtin_amdgcn_s_setprio(0);

    __syncthreads();
  }

  const size_t rb = (size_t)(z * NH + h) * L_SEQ + q0 + w * 16;
  float linv[4];
#pragma unroll
  for (int r = 0; r < 4; ++r) linv[r] = 1.f / __shfl(l_run, quad * 4 + r);
#pragma unroll
  for (int r = 0; r < 4; ++r) {
    size_t row = rb + quad * 4 + r;
#pragma unroll
    for (int n2 = 0; n2 < 8; ++n2)
      Opart[row * HD + n2 * 16 + l15] = __float2bfloat16(o[n2][r] * linv[r]);
  }
  if (quad == 0) ml[rb + l15] = make_float2(m_run, l_run);
}

// ---------------------------------------------------------------------------
// Combine the four KV-split chunks.
// ---------------------------------------------------------------------------
__global__ __launch_bounds__(256)
void attn_combine4(const __hip_bfloat16* __restrict__ Opart,
                   const float2* __restrict__ ml,
                   __hip_bfloat16* __restrict__ out) {
  const int h  = blockIdx.y;
  const int q  = blockIdx.x * 16 + (threadIdx.x >> 4);
  const int d8 = (threadIdx.x & 15) * 8;
  size_t idx[NZ];
  float2 a[NZ];
#pragma unroll
  for (int zz = 0; zz < NZ; ++zz) {
    idx[zz] = ((size_t)zz * NH + h) * L_SEQ + q;
    a[zz] = ml[idx[zz]];
  }
  float M = fmaxf(fmaxf(a[0].x, a[1].x), fmaxf(a[2].x, a[3].x));
  float wz[NZ];
  float tot = 0.f;
#pragma unroll
  for (int zz = 0; zz < NZ; ++zz) {
    wz[zz] = __expf(a[zz].x - M) * a[zz].y;
    tot += wz[zz];
  }
  float inv = 1.f / tot;
  float acc[8] = {0.f, 0.f, 0.f, 0.f, 0.f, 0.f, 0.f, 0.f};
#pragma unroll
  for (int zz = 0; zz < NZ; ++zz) {
    short8 ov = *(const short8*)&Opart[idx[zz] * HD + d8];
#pragma unroll
    for (int j = 0; j < 8; ++j) acc[j] += wz[zz] * bits2f(ov[j]);
  }
  short8 r;
#pragma unroll
  for (int j = 0; j < 8; ++j) r[j] = bf16bits(acc[j] * inv);
  *(short8*)&out[(size_t)q * DIM + h * HD + d8] = r;
}

// ---------------------------------------------------------------------------
extern "C" void kernel_launch(void* const* d_in, const int* in_sizes, int n_in,
                              void* d_out, int out_size, void* d_ws, size_t ws_size,
                              hipStream_t stream) {
  const float* x       = (const float*)d_in[0];
  const float* pe      = (const float*)d_in[1];
  const float* qkv_w   = (const float*)d_in[2];
  const float* q_scale = (const float*)d_in[3];
  const float* k_scale = (const float*)d_in[4];
  const float* proj_w  = (const float*)d_in[5];
  const float* proj_b  = (const float*)d_in[6];
  float* out = (float*)d_out;

  // Workspace (67,108,864 B), phase-disjoint reuse:
  //  p1 cast+gemm:  xb [0,8.4M) | wb [8.4,33.6M) | Cq [33.6,58.8M)
  //  p2 epilogue:   reads Cq; Qb [0,8.4M) Kb [8.4,16.8M) Vt [16.8,25.2M)
  //  p3 attn z=4:   reads Qb/Kb/Vt; Opart [33.6,67.1M) (over dead Cq+tail),
  //                 ml [25.2,26.2M)
  //  p4 combine:    reads Opart/ml; attn_out [0,8.4M) (over dead Qb)
  //  p5 cast_pw:    pwb [33.6,42.0M) (over dead Opart)  -- AFTER combine
  //  p6 proj:       reads attn_out + pwb; writes out
  char* base = (char*)d_ws;
  __hip_bfloat16* xb       = (__hip_bfloat16*)base;
  __hip_bfloat16* wb       = (__hip_bfloat16*)(base + 8388608);
  __hip_bfloat16* Cq       = (__hip_bfloat16*)(base + 33554432);
  __hip_bfloat16* Qb       = (__hip_bfloat16*)base;
  __hip_bfloat16* Kb       = (__hip_bfloat16*)(base + 8388608);
  __hip_bfloat16* Vt       = (__hip_bfloat16*)(base + 16777216);
  __hip_bfloat16* Opart    = (__hip_bfloat16*)(base + 33554432);
  float2*         ml       = (float2*)(base + 25165824);
  __hip_bfloat16* attn_out = (__hip_bfloat16*)base;
  __hip_bfloat16* pwb      = (__hip_bfloat16*)(base + 33554432);

  static bool attr_done = false;
  if (!attr_done) {
    hipFuncSetAttribute((const void*)gemm_qkv_256,
                        hipFuncAttributeMaxDynamicSharedMemorySize, 131072);
    attr_done = true;
  }

  cast2_bf16<<<dim3((DIM * DIM + TDIM * DIM) / (256 * 8)), 256, 0, stream>>>(
      x, xb, qkv_w, wb);

  gemm_qkv_256<<<dim3((TDIM / 256) * (L_SEQ / 256)), 512, 131072, stream>>>(xb, wb, Cq);

  qkv_epilogue<<<dim3(1024), 256, 0, stream>>>(Cq, q_scale, k_scale, pe, Qb, Kb, Vt);

  attn_mfma<<<dim3(NZ * NH * (L_SEQ / 64)), 256, 0, stream>>>(Qb, Kb, Vt, Opart, ml);

  attn_combine4<<<dim3(L_SEQ / 16, NH), 256, 0, stream>>>(Opart, ml, attn_out);

  cast_bf16<<<dim3(DIM * DIM / (256 * 8)), 256, 0, stream>>>(proj_w, pwb, DIM * DIM);

  gemm_proj<<<dim3(DIM / 128, DIM / 128), 256, 0, stream>>>(
      attn_out, pwb, proj_b, out, L_SEQ, DIM, DIM);
}

// Round 4
// 318.609 us; speedup vs baseline: 1.0711x; 1.0328x over previous
//
#include <hip/hip_runtime.h>
#include <hip/hip_bf16.h>
#include <math.h>

#define L_SEQ 2048
#define DIM   2048
#define NH    16
#define HD    128
#define TDIM  6144

typedef __attribute__((ext_vector_type(8))) short short8;
typedef __attribute__((ext_vector_type(4))) float f32x4;
typedef __attribute__((ext_vector_type(16))) float f32x16;
typedef __attribute__((ext_vector_type(4))) unsigned int u32x4;

// async global->LDS, 16 B per lane. LDS dest = wave-uniform base + lane*16.
__device__ __forceinline__ void gl_lds16(const void* g, void* l) {
  __builtin_amdgcn_global_load_lds(
      (const __attribute__((address_space(1))) unsigned int*)g,
      (__attribute__((address_space(3))) unsigned int*)l, 16, 0, 0);
}

__device__ __forceinline__ short bf16bits(float x) {
  __hip_bfloat16 h = __float2bfloat16(x);
  return *(short*)&h;
}

__device__ __forceinline__ float bits2f(short s) {
  unsigned int u = ((unsigned int)(unsigned short)s) << 16;
  return __uint_as_float(u);
}

__device__ __forceinline__ unsigned int pack_bf16(float a, float b) {
  __hip_bfloat162 h = __float22bfloat162_rn(make_float2(a, b));
  return *(unsigned int*)&h;
}

// ---------------------------------------------------------------------------
// fused fp32 -> bf16 cast of x (4M elems) then qkv_w (12M elems).
// ---------------------------------------------------------------------------
__global__ __launch_bounds__(256)
void cast2_bf16(const float* __restrict__ a, __hip_bfloat16* __restrict__ oa,
                const float* __restrict__ b, __hip_bfloat16* __restrict__ ob) {
  int i = (blockIdx.x * 256 + threadIdx.x) * 8;
  const float* src;
  __hip_bfloat16* dst;
  int off;
  if (i < DIM * DIM) { src = a; dst = oa; off = i; }
  else               { src = b; dst = ob; off = i - DIM * DIM; }
  float4 v0 = *(const float4*)(src + off);
  float4 v1 = *(const float4*)(src + off + 4);
  short8 o;
  o[0] = bf16bits(v0.x); o[1] = bf16bits(v0.y); o[2] = bf16bits(v0.z); o[3] = bf16bits(v0.w);
  o[4] = bf16bits(v1.x); o[5] = bf16bits(v1.y); o[6] = bf16bits(v1.z); o[7] = bf16bits(v1.w);
  *(short8*)(dst + off) = o;
}

__global__ __launch_bounds__(256)
void cast_bf16(const float* __restrict__ in, __hip_bfloat16* __restrict__ out, int n) {
  int i = (blockIdx.x * 256 + threadIdx.x) * 8;
  if (i >= n) return;
  float4 a = *(const float4*)(in + i);
  float4 b = *(const float4*)(in + i + 4);
  short8 o;
  o[0] = bf16bits(a.x); o[1] = bf16bits(a.y); o[2] = bf16bits(a.z); o[3] = bf16bits(a.w);
  o[4] = bf16bits(b.x); o[5] = bf16bits(b.y); o[6] = bf16bits(b.z); o[7] = bf16bits(b.w);
  *(short8*)(out + i) = o;
}

// ---------------------------------------------------------------------------
// QKV GEMM, deep-pipelined 256x256 tile (T3+T4+T5). Verified R1.
// ---------------------------------------------------------------------------
#define QKV_N 6144
#define QKV_K 2048

__global__ __launch_bounds__(512, 2)
void gemm_qkv_256(const __hip_bfloat16* __restrict__ A,
                  const __hip_bfloat16* __restrict__ B,
                  __hip_bfloat16* __restrict__ C) {
  extern __shared__ char smem[];
  const int tid  = threadIdx.x;
  const int lane = tid & 63, w = tid >> 6;
  const int l15  = lane & 15, quad = lane >> 4;
  const int wm   = w >> 2, wn = w & 3;

  const int orig = blockIdx.x;
  const int by = orig & 7;    // M-tile: 8 tiles of 256
  const int bx = orig >> 3;   // N-tile: 24 tiles of 256
  const int m0 = by * 256, n0 = bx * 256;

  const int ar0 = tid >> 2,         aq0 = tid & 3;
  const int ar1 = (512 + tid) >> 2, aq1 = (512 + tid) & 3;
  const __hip_bfloat16* pA0 = A + (size_t)(m0 + ar0) * QKV_K + aq0 * 8;
  const __hip_bfloat16* pA1 = A + (size_t)(m0 + ar1) * QKV_K + aq1 * 8;
  const __hip_bfloat16* pB0 = B + (size_t)(n0 + ar0) * QKV_K + aq0 * 8;
  const __hip_bfloat16* pB1 = B + (size_t)(n0 + ar1) * QKV_K + aq1 * 8;
  const int dst0 = w * 1024;

  f32x4 acc[8][4];
#pragma unroll
  for (int mi = 0; mi < 8; ++mi)
#pragma unroll
    for (int ni = 0; ni < 4; ++ni) acc[mi][ni] = (f32x4){0.f, 0.f, 0.f, 0.f};

  const int aoff = ((wm * 128 + l15) * 32 + quad * 8) * 2;
  const int boff = ((wn * 64 + l15) * 32 + quad * 8) * 2;

#pragma unroll
  for (int p = 0; p < 3; ++p) {
    char* Sp = smem + p * 32768;
    gl_lds16(pA0 + p * 32, Sp + dst0);
    gl_lds16(pA1 + p * 32, Sp + dst0 + 8192);
    gl_lds16(pB0 + p * 32, Sp + 16384 + dst0);
    gl_lds16(pB1 + p * 32, Sp + 16384 + dst0 + 8192);
  }
  asm volatile("s_waitcnt vmcnt(8)\n\ts_barrier" ::: "memory");

  for (int tb = 0; tb < 64; tb += 4) {
#pragma unroll
    for (int u = 0; u < 4; ++u) {
      const int t  = tb + u;
      const char* As = smem + u * 32768;
      const char* Bs = As + 16384;
      const int tn = (t + 3) & 63;
      char* Sn = smem + ((u + 3) & 3) * 32768;

      short8 a[8];
#pragma unroll
      for (int mi = 0; mi < 8; ++mi)
        a[mi] = *(const short8*)(As + aoff + mi * 1024);
      short8 b0 = *(const short8*)(Bs + boff);
      short8 b1 = *(const short8*)(Bs + boff + 1024);
      gl_lds16(pA0 + tn * 32, Sn + dst0);
      gl_lds16(pA1 + tn * 32, Sn + dst0 + 8192);
      __builtin_amdgcn_s_barrier();
      __builtin_amdgcn_s_setprio(1);
#pragma unroll
      for (int mi = 0; mi < 8; ++mi) {
        acc[mi][0] = __builtin_amdgcn_mfma_f32_16x16x32_bf16(a[mi], b0, acc[mi][0], 0, 0, 0);
        acc[mi][1] = __builtin_amdgcn_mfma_f32_16x16x32_bf16(a[mi], b1, acc[mi][1], 0, 0, 0);
      }
      __builtin_amdgcn_s_setprio(0);
      __builtin_amdgcn_s_barrier();

      short8 b2 = *(const short8*)(Bs + boff + 2048);
      short8 b3 = *(const short8*)(Bs + boff + 3072);
      gl_lds16(pB0 + tn * 32, Sn + 16384 + dst0);
      gl_lds16(pB1 + tn * 32, Sn + 16384 + dst0 + 8192);
      asm volatile("s_waitcnt vmcnt(8)\n\ts_barrier" ::: "memory");
      __builtin_amdgcn_s_setprio(1);
#pragma unroll
      for (int mi = 0; mi < 8; ++mi) {
        acc[mi][2] = __builtin_amdgcn_mfma_f32_16x16x32_bf16(a[mi], b2, acc[mi][2], 0, 0, 0);
        acc[mi][3] = __builtin_amdgcn_mfma_f32_16x16x32_bf16(a[mi], b3, acc[mi][3], 0, 0, 0);
      }
      __builtin_amdgcn_s_setprio(0);
      __builtin_amdgcn_s_barrier();
    }
  }

  const int crow = m0 + wm * 128 + quad * 4;
  const int ccol = n0 + wn * 64 + l15;
#pragma unroll
  for (int mi = 0; mi < 8; ++mi)
#pragma unroll
    for (int ni = 0; ni < 4; ++ni)
#pragma unroll
      for (int r = 0; r < 4; ++r)
        C[(size_t)(crow + mi * 16 + r) * QKV_N + ccol + ni * 16] =
            __float2bfloat16(acc[mi][ni][r]);
}

// ---------------------------------------------------------------------------
// Epilogue: reads C[2048][6144] bf16 (L3-resident). Verified R1.
// ---------------------------------------------------------------------------
__global__ __launch_bounds__(256)
void qkv_epilogue(const __hip_bfloat16* __restrict__ C,
                  const float* __restrict__ q_scale, const float* __restrict__ k_scale,
                  const float* __restrict__ pe,
                  __hip_bfloat16* __restrict__ Qb, __hip_bfloat16* __restrict__ Kb,
                  __hip_bfloat16* __restrict__ Vt) {
  const int bid = blockIdx.x;
  const int t = threadIdx.x;
  if (bid < 512) {
    const int sec = bid >> 8;          // 0 = q, 1 = k
    const int h   = (bid >> 4) & 15;
    const int rb  = bid & 15;          // 16 row-blocks of 128
    const float* scale = sec ? k_scale : q_scale;
    const float qmul = sec ? 1.0f : 0.08838834764831845f;
    __hip_bfloat16* dst = sec ? Kb : Qb;

    const int row = t >> 1, half = t & 1;
    const int l = rb * 128 + row;
    const __hip_bfloat16* grow = C + (size_t)l * TDIM + sec * DIM + h * HD + half * 64;

    float ss = 0.f;
#pragma unroll
    for (int c8 = 0; c8 < 64; c8 += 8) {
      short8 v8 = *(const short8*)(grow + c8);
#pragma unroll
      for (int j = 0; j < 8; ++j) { float f = bits2f(v8[j]); ss += f * f; }
    }
    ss += __shfl_xor(ss, 1);
    const float rrms = rsqrtf(ss * (1.f / 128.f) + 1e-6f);

    const float* perow = pe + (size_t)l * 256 + half * 128;
    __hip_bfloat16* drow = dst + ((size_t)h * L_SEQ + l) * HD + half * 64;

#pragma unroll
    for (int c8 = 0; c8 < 64; c8 += 8) {
      short8 v8 = *(const short8*)(grow + c8);
      float f[8];
#pragma unroll
      for (int j = 0; j < 8; ++j)
        f[j] = bits2f(v8[j]) * rrms * scale[half * 64 + c8 + j];
      short8 o;
#pragma unroll
      for (int p = 0; p < 4; ++p) {
        float4 pp = *(const float4*)(perow + c8 * 2 + p * 4);
        float e = f[2 * p], od = f[2 * p + 1];
        o[2 * p]     = bf16bits((pp.x * e + pp.y * od) * qmul);
        o[2 * p + 1] = bf16bits((pp.z * e + pp.w * od) * qmul);
      }
      *(short8*)(drow + c8) = o;
    }
  } else {
    __shared__ short Tt[128 * 72];
    const int vb = bid - 512;
    const int h = vb >> 5, lb = vb & 31;
    const int l0 = lb * 64;
#pragma unroll
    for (int k = 0; k < 4; ++k) {
      int idx = t + k * 256;
      int row = idx >> 4, c = idx & 15;
      short8 v = *(const short8*)(C + (size_t)(l0 + row) * TDIM + 2 * DIM + h * HD + c * 8);
#pragma unroll
      for (int j = 0; j < 8; ++j) Tt[(c * 8 + j) * 72 + row] = v[j];
    }
    __syncthreads();
    const int d = t >> 1, lh = t & 1;
    __hip_bfloat16* vrow = Vt + ((size_t)h * HD + d) * L_SEQ + l0 + lh * 32;
#pragma unroll
    for (int k = 0; k < 4; ++k) {
      short8 o = *(const short8*)&Tt[d * 72 + lh * 32 + k * 8];
      *(short8*)(vrow + k * 8) = o;
    }
  }
}

// ---------------------------------------------------------------------------
// bf16 MFMA GEMM (m97 structure) — proj only (fp32 out + bias). Verified.
// ---------------------------------------------------------------------------
__global__ __launch_bounds__(256)
void gemm_proj(const __hip_bfloat16* __restrict__ A, const __hip_bfloat16* __restrict__ B,
               const float* __restrict__ bias, float* __restrict__ C,
               int M, int N, int K) {
  const int n0 = blockIdx.x * 128, m0 = blockIdx.y * 128;
  const int t = threadIdx.x, lane = t & 63, w = t >> 6;
  const int l15 = lane & 15, quad = lane >> 4;
  const int wm = (w & 1) * 64, wn = (w >> 1) * 64;

  __shared__ __align__(16) __hip_bfloat16 As[128 * 32];
  __shared__ __align__(16) __hip_bfloat16 Bs[128 * 32];

  f32x4 acc[4][4];
#pragma unroll
  for (int mt = 0; mt < 4; ++mt)
#pragma unroll
    for (int nt = 0; nt < 4; ++nt) acc[mt][nt] = (f32x4){0.f, 0.f, 0.f, 0.f};

  const int arow  = lane >> 2;
  const int acol8 = (lane & 3) * 8;
  const __hip_bfloat16* Ab = A + (size_t)(m0 + w * 16 + arow) * K + acol8;
  const __hip_bfloat16* Bb = B + (size_t)(n0 + w * 16 + arow) * K + acol8;
  __hip_bfloat16* As_base = As + (size_t)(w * 16) * 32;
  __hip_bfloat16* Bs_base = Bs + (size_t)(w * 16) * 32;

  for (int kb = 0; kb < K; kb += 32) {
    gl_lds16(Ab + kb,                As_base);
    gl_lds16(Ab + kb + (size_t)64*K, As_base + 64 * 32);
    gl_lds16(Bb + kb,                Bs_base);
    gl_lds16(Bb + kb + (size_t)64*K, Bs_base + 64 * 32);
    __syncthreads();

    short8 am[4], bn[4];
#pragma unroll
    for (int mt = 0; mt < 4; ++mt)
      am[mt] = *(const short8*)&As[(size_t)(wm + mt*16 + l15) * 32 + quad * 8];
#pragma unroll
    for (int nt = 0; nt < 4; ++nt)
      bn[nt] = *(const short8*)&Bs[(size_t)(wn + nt*16 + l15) * 32 + quad * 8];
#pragma unroll
    for (int mt = 0; mt < 4; ++mt)
#pragma unroll
      for (int nt = 0; nt < 4; ++nt)
        acc[mt][nt] = __builtin_amdgcn_mfma_f32_16x16x32_bf16(am[mt], bn[nt], acc[mt][nt], 0, 0, 0);
    __syncthreads();
  }

#pragma unroll
  for (int mt = 0; mt < 4; ++mt)
#pragma unroll
    for (int nt = 0; nt < 4; ++nt) {
      int col = n0 + wn + nt * 16 + l15;
#pragma unroll
      for (int r = 0; r < 4; ++r) {
        int row = m0 + wm + mt * 16 + quad * 4 + r;
        C[(size_t)row * N + col] = acc[mt][nt][r] + bias[col];
      }
    }
}

// ---------------------------------------------------------------------------
// Flash attention v4: 32x32 swapped-QK^T. q = lane&31 (lane-local softmax
// state), k spread over regs + lane>>5. P redistribution for PV via
// cvt_pk pairs + 4x v_permlane32_swap (T12) — no ds_bpermute.
// PV computes O^T = mfma(A=V^T, B=P); O^T -> coalesced store via swizzled
// LDS round-trip (reuses Ks/Vs after the KV loop).
// z=4 split, 1024 blocks, 4 waves x 32q = 128 q/block, KVBLK=64,
// verified staging + XOR swizzles from R3.
// ---------------------------------------------------------------------------
#define NZ 4
#define ZLEN (L_SEQ / NZ)

__global__ __launch_bounds__(256, 3)
void attn_mfma(const __hip_bfloat16* __restrict__ Qb,
               const __hip_bfloat16* __restrict__ Kb,
               const __hip_bfloat16* __restrict__ Vt,
               __hip_bfloat16* __restrict__ Opart, float2* __restrict__ ml) {
  // 1024 blocks; bijective XCD swizzle; XCD c -> heads 2c, 2c+1.
  const int orig = blockIdx.x;
  const int wg   = (orig & 7) * 128 + (orig >> 3);
  const int h    = wg >> 6;
  const int rem  = wg & 63;
  const int z    = rem >> 4;
  const int q0   = (rem & 15) * 128;
  const int t    = threadIdx.x;
  const int lane = t & 63, w = t >> 6;
  const int l31  = lane & 31;   // q column / k row / d row
  const int u    = lane >> 5;   // half selector

  __shared__ __align__(16) __hip_bfloat16 Ks[64 * 128];
  __shared__ __align__(16) __hip_bfloat16 Vs[128 * 64];

  const __hip_bfloat16* kbase = Kb + (size_t)h * L_SEQ * HD;
  const __hip_bfloat16* vbase = Vt + (size_t)h * HD * L_SEQ;

  // Q fragment (B-operand of 32x32x16): lane holds Q[q][hh*16 + u*8 + j]
  short8 aq[8];
  {
    const __hip_bfloat16* qb = Qb + ((size_t)h * L_SEQ + q0 + w * 32 + l31) * HD + u * 8;
#pragma unroll
    for (int hh = 0; hh < 8; ++hh)
      aq[hh] = *(const short8*)(qb + hh * 16);
  }

  f32x16 o[4];
#pragma unroll
  for (int dt = 0; dt < 4; ++dt)
#pragma unroll
    for (int r = 0; r < 16; ++r) o[dt][r] = 0.f;
  float m_run = -1e30f, l_run = 0.f;

  for (int kt = 0; kt < ZLEN / 64; ++kt) {
    const int k0 = z * ZLEN + kt * 64;
    // ---- staging: verified R3 pattern (linear dest, pre-swizzled source) ----
#pragma unroll
    for (int i = 0; i < 4; ++i) {
      int krow = w * 16 + i * 4 + (lane >> 4);
      int kch  = (lane & 15) ^ (krow & 7);
      gl_lds16(kbase + (size_t)(k0 + krow) * HD + kch * 8,
               &Ks[(w * 16 + i * 4) * 128]);
    }
#pragma unroll
    for (int i = 0; i < 4; ++i) {
      int vrow = w * 32 + i * 8 + (lane >> 3);
      int vch  = (lane & 7) ^ (vrow & 7);
      gl_lds16(vbase + (size_t)vrow * L_SEQ + k0 + vch * 8,
               &Vs[(w * 32 + i * 8) * 64]);
    }
    __syncthreads();

#pragma unroll
    for (int ks = 0; ks < 2; ++ks) {
      // ---- QK^T: S[k = regs/u, q = l31] ----
      const int krow = ks * 32 + l31;
      const char* krowp = (const char*)Ks + krow * 256;
      const int ksw = krow & 7;
      f32x16 s;
#pragma unroll
      for (int r = 0; r < 16; ++r) s[r] = 0.f;
      __builtin_amdgcn_s_setprio(1);
#pragma unroll
      for (int hh = 0; hh < 8; ++hh) {
        short8 ak = *(const short8*)(krowp + ((hh * 2 + u) ^ ksw) * 16);
        s = __builtin_amdgcn_mfma_f32_32x32x16_bf16(ak, aq[hh], s, 0, 0, 0);
      }
      __builtin_amdgcn_s_setprio(0);

      // ---- softmax: k-reduce = 15 in-lane + 1 cross-half ----
      float rm = s[0];
#pragma unroll
      for (int r = 1; r < 16; ++r) rm = fmaxf(rm, s[r]);
      rm = fmaxf(rm, __shfl_xor(rm, 32));

      // T13 defer-max (wave-uniform)
      if (!__all(rm <= m_run + 8.f)) {
        float mnew = fmaxf(m_run, rm);
        float alpha = __expf(m_run - mnew);
        m_run = mnew;
        l_run *= alpha;
#pragma unroll
        for (int dt = 0; dt < 4; ++dt)
#pragma unroll
          for (int r = 0; r < 16; ++r) o[dt][r] *= alpha;
      }

      float sum = 0.f;
#pragma unroll
      for (int r = 0; r < 16; ++r) {
        float p = __expf(s[r] - m_run);
        s[r] = p;
        sum += p;
      }
      sum += __shfl_xor(sum, 32);
      l_run += sum;

      // ---- P -> bf16 B-fragments: 8 cvt_pk + 4 permlane32_swap ----
      // W words: k-pairs (4u,4u+1),(4u+2,4u+3),(8+4u,..),(16+..),(24+..)
      unsigned int W0 = pack_bf16(s[0],  s[1]),  W1 = pack_bf16(s[2],  s[3]);
      unsigned int W2 = pack_bf16(s[4],  s[5]),  W3 = pack_bf16(s[6],  s[7]);
      unsigned int W4 = pack_bf16(s[8],  s[9]),  W5 = pack_bf16(s[10], s[11]);
      unsigned int W6 = pack_bf16(s[12], s[13]), W7 = pack_bf16(s[14], s[15]);
      // swap(W0,W2): W0 <- B word j0 (both halves), W2 <- B word j2. etc.
      asm("v_permlane32_swap_b32 %0, %1" : "+v"(W0), "+v"(W2));
      asm("v_permlane32_swap_b32 %0, %1" : "+v"(W1), "+v"(W3));
      asm("v_permlane32_swap_b32 %0, %1" : "+v"(W4), "+v"(W6));
      asm("v_permlane32_swap_b32 %0, %1" : "+v"(W5), "+v"(W7));
      u32x4 pb0 = {W0, W1, W2, W3};   // k-chunk ks*32 + 0..15
      u32x4 pb1 = {W4, W5, W6, W7};   // k-chunk ks*32 + 16..31
      short8 ap0 = *(short8*)&pb0;
      short8 ap1 = *(short8*)&pb1;

      // ---- PV: O^T[d, q] += V^T[d, k] * P[k, q] ----
      __builtin_amdgcn_s_setprio(1);
#pragma unroll
      for (int dt = 0; dt < 4; ++dt) {
        const int d = dt * 32 + l31;
        const char* vrowp = (const char*)Vs + d * 128;
        const int vsw = d & 7;
        short8 av0 = *(const short8*)(vrowp + ((ks * 4 + u) ^ vsw) * 16);
        o[dt] = __builtin_amdgcn_mfma_f32_32x32x16_bf16(av0, ap0, o[dt], 0, 0, 0);
        short8 av1 = *(const short8*)(vrowp + ((ks * 4 + 2 + u) ^ vsw) * 16);
        o[dt] = __builtin_amdgcn_mfma_f32_32x32x16_bf16(av1, ap1, o[dt], 0, 0, 0);
      }
      __builtin_amdgcn_s_setprio(0);
    }
    __syncthreads();
  }

  // ---- epilogue: normalize (per-lane!) and transpose via swizzled LDS ----
  const float linv = 1.f / l_run;
  char* Ot = (char*)Ks + w * 8192;    // per-wave 32x128 bf16 region
  const int qsw = l31 & 7;
#pragma unroll
  for (int dt = 0; dt < 4; ++dt)
#pragma unroll
    for (int p = 0; p < 8; ++p) {
      unsigned int v = pack_bf16(o[dt][2 * p] * linv, o[dt][2 * p + 1] * linv);
      int dpair = dt * 16 + (p & 1) + (p >> 1) * 4 + 2 * u;   // d/2 of the pair
      *(unsigned int*)(Ot + l31 * 256 + ((dpair >> 2) ^ qsw) * 16 + (dpair & 3) * 4) = v;
    }
  __syncthreads();
  {
    const int qr = lane >> 1, half = lane & 1;
    const char* Orow = (char*)Ks + w * 8192 + qr * 256;
    __hip_bfloat16* gout =
        Opart + ((size_t)(z * NH + h) * L_SEQ + q0 + w * 32 + qr) * HD;
#pragma unroll
    for (int c8 = 0; c8 < 8; ++c8) {
      int chunk = half * 8 + c8;
      short8 v = *(const short8*)(Orow + ((chunk ^ (qr & 7)) * 16));
      *(short8*)(gout + chunk * 8) = v;
    }
  }
  if (lane < 32) {
    size_t rb = (size_t)(z * NH + h) * L_SEQ + q0 + w * 32;
    ml[rb + l31] = make_float2(m_run, l_run);
  }
}

// ---------------------------------------------------------------------------
// Combine the four KV-split chunks. Verified R3.
// ---------------------------------------------------------------------------
__global__ __launch_bounds__(256)
void attn_combine4(const __hip_bfloat16* __restrict__ Opart,
                   const float2* __restrict__ ml,
                   __hip_bfloat16* __restrict__ out) {
  const int h  = blockIdx.y;
  const int q  = blockIdx.x * 16 + (threadIdx.x >> 4);
  const int d8 = (threadIdx.x & 15) * 8;
  size_t idx[NZ];
  float2 a[NZ];
#pragma unroll
  for (int zz = 0; zz < NZ; ++zz) {
    idx[zz] = ((size_t)zz * NH + h) * L_SEQ + q;
    a[zz] = ml[idx[zz]];
  }
  float M = fmaxf(fmaxf(a[0].x, a[1].x), fmaxf(a[2].x, a[3].x));
  float wz[NZ];
  float tot = 0.f;
#pragma unroll
  for (int zz = 0; zz < NZ; ++zz) {
    wz[zz] = __expf(a[zz].x - M) * a[zz].y;
    tot += wz[zz];
  }
  float inv = 1.f / tot;
  float acc[8] = {0.f, 0.f, 0.f, 0.f, 0.f, 0.f, 0.f, 0.f};
#pragma unroll
  for (int zz = 0; zz < NZ; ++zz) {
    short8 ov = *(const short8*)&Opart[idx[zz] * HD + d8];
#pragma unroll
    for (int j = 0; j < 8; ++j) acc[j] += wz[zz] * bits2f(ov[j]);
  }
  short8 r;
#pragma unroll
  for (int j = 0; j < 8; ++j) r[j] = bf16bits(acc[j] * inv);
  *(short8*)&out[(size_t)q * DIM + h * HD + d8] = r;
}

// ---------------------------------------------------------------------------
extern "C" void kernel_launch(void* const* d_in, const int* in_sizes, int n_in,
                              void* d_out, int out_size, void* d_ws, size_t ws_size,
                              hipStream_t stream) {
  const float* x       = (const float*)d_in[0];
  const float* pe      = (const float*)d_in[1];
  const float* qkv_w   = (const float*)d_in[2];
  const float* q_scale = (const float*)d_in[3];
  const float* k_scale = (const float*)d_in[4];
  const float* proj_w  = (const float*)d_in[5];
  const float* proj_b  = (const float*)d_in[6];
  float* out = (float*)d_out;

  // Workspace (67,108,864 B), phase-disjoint reuse:
  //  p1 cast+gemm:  xb [0,8.4M) | wb [8.4,33.6M) | Cq [33.6,58.8M)
  //  p2 epilogue:   reads Cq; Qb [0,8.4M) Kb [8.4,16.8M) Vt [16.8,25.2M)
  //  p3 attn z=4:   reads Qb/Kb/Vt; Opart [33.6,67.1M), ml [25.2,26.2M)
  //  p4 combine:    reads Opart/ml; attn_out [0,8.4M) (over dead Qb)
  //  p5 cast_pw:    pwb [33.6,42.0M) (over dead Opart)  -- AFTER combine
  //  p6 proj:       reads attn_out + pwb; writes out
  char* base = (char*)d_ws;
  __hip_bfloat16* xb       = (__hip_bfloat16*)base;
  __hip_bfloat16* wb       = (__hip_bfloat16*)(base + 8388608);
  __hip_bfloat16* Cq       = (__hip_bfloat16*)(base + 33554432);
  __hip_bfloat16* Qb       = (__hip_bfloat16*)base;
  __hip_bfloat16* Kb       = (__hip_bfloat16*)(base + 8388608);
  __hip_bfloat16* Vt       = (__hip_bfloat16*)(base + 16777216);
  __hip_bfloat16* Opart    = (__hip_bfloat16*)(base + 33554432);
  float2*         ml       = (float2*)(base + 25165824);
  __hip_bfloat16* attn_out = (__hip_bfloat16*)base;
  __hip_bfloat16* pwb      = (__hip_bfloat16*)(base + 33554432);

  static bool attr_done = false;
  if (!attr_done) {
    hipFuncSetAttribute((const void*)gemm_qkv_256,
                        hipFuncAttributeMaxDynamicSharedMemorySize, 131072);
    attr_done = true;
  }

  cast2_bf16<<<dim3((DIM * DIM + TDIM * DIM) / (256 * 8)), 256, 0, stream>>>(
      x, xb, qkv_w, wb);

  gemm_qkv_256<<<dim3((TDIM / 256) * (L_SEQ / 256)), 512, 131072, stream>>>(xb, wb, Cq);

  qkv_epilogue<<<dim3(1024), 256, 0, stream>>>(Cq, q_scale, k_scale, pe, Qb, Kb, Vt);

  attn_mfma<<<dim3(NZ * NH * (L_SEQ / 128)), 256, 0, stream>>>(Qb, Kb, Vt, Opart, ml);

  attn_combine4<<<dim3(L_SEQ / 16, NH), 256, 0, stream>>>(Opart, ml, attn_out);

  cast_bf16<<<dim3(DIM * DIM / (256 * 8)), 256, 0, stream>>>(proj_w, pwb, DIM * DIM);

  gemm_proj<<<dim3(DIM / 128, DIM / 128), 256, 0, stream>>>(
      attn_out, pwb, proj_b, out, L_SEQ, DIM, DIM);
}

// Round 5
// 288.672 us; speedup vs baseline: 1.1822x; 1.1037x over previous
//
#include <hip/hip_runtime.h>
#include <hip/hip_bf16.h>
#include <math.h>

#define L_SEQ 2048
#define DIM   2048
#define NH    16
#define HD    128
#define TDIM  6144

typedef __attribute__((ext_vector_type(8))) short short8;
typedef __attribute__((ext_vector_type(4))) float f32x4;
typedef __attribute__((ext_vector_type(16))) float f32x16;
typedef __attribute__((ext_vector_type(4))) unsigned int u32x4;

// async global->LDS, 16 B per lane. LDS dest = wave-uniform base + lane*16.
__device__ __forceinline__ void gl_lds16(const void* g, void* l) {
  __builtin_amdgcn_global_load_lds(
      (const __attribute__((address_space(1))) unsigned int*)g,
      (__attribute__((address_space(3))) unsigned int*)l, 16, 0, 0);
}

__device__ __forceinline__ short bf16bits(float x) {
  __hip_bfloat16 h = __float2bfloat16(x);
  return *(short*)&h;
}

__device__ __forceinline__ float bits2f(short s) {
  unsigned int u = ((unsigned int)(unsigned short)s) << 16;
  return __uint_as_float(u);
}

__device__ __forceinline__ unsigned int pack_bf16(float a, float b) {
  __hip_bfloat162 h = __float22bfloat162_rn(make_float2(a, b));
  return *(unsigned int*)&h;
}

// ---------------------------------------------------------------------------
// fused fp32 -> bf16 cast of x (4M elems) then qkv_w (12M elems).
// ---------------------------------------------------------------------------
__global__ __launch_bounds__(256)
void cast2_bf16(const float* __restrict__ a, __hip_bfloat16* __restrict__ oa,
                const float* __restrict__ b, __hip_bfloat16* __restrict__ ob) {
  int i = (blockIdx.x * 256 + threadIdx.x) * 8;
  const float* src;
  __hip_bfloat16* dst;
  int off;
  if (i < DIM * DIM) { src = a; dst = oa; off = i; }
  else               { src = b; dst = ob; off = i - DIM * DIM; }
  float4 v0 = *(const float4*)(src + off);
  float4 v1 = *(const float4*)(src + off + 4);
  short8 o;
  o[0] = bf16bits(v0.x); o[1] = bf16bits(v0.y); o[2] = bf16bits(v0.z); o[3] = bf16bits(v0.w);
  o[4] = bf16bits(v1.x); o[5] = bf16bits(v1.y); o[6] = bf16bits(v1.z); o[7] = bf16bits(v1.w);
  *(short8*)(dst + off) = o;
}

__global__ __launch_bounds__(256)
void cast_bf16(const float* __restrict__ in, __hip_bfloat16* __restrict__ out, int n) {
  int i = (blockIdx.x * 256 + threadIdx.x) * 8;
  if (i >= n) return;
  float4 a = *(const float4*)(in + i);
  float4 b = *(const float4*)(in + i + 4);
  short8 o;
  o[0] = bf16bits(a.x); o[1] = bf16bits(a.y); o[2] = bf16bits(a.z); o[3] = bf16bits(a.w);
  o[4] = bf16bits(b.x); o[5] = bf16bits(b.y); o[6] = bf16bits(b.z); o[7] = bf16bits(b.w);
  *(short8*)(out + i) = o;
}

// ---------------------------------------------------------------------------
// QKV GEMM, deep-pipelined 256x256 tile (T3+T4+T5), R5:
//  + LDS XOR swizzle q' = q ^ ((row>>1)&3): kills the 8-way bank conflict of
//    64B rows (bank-quad = 4(row&1) + q' covers all 8 slots over 8 rows).
//    Applied as pre-swizzled global SOURCE (linear gl_lds dest) + swizzled
//    read offset (both-sides involution, rule #21).
//  + XCD 2x4 chunking: each XCD owns 4 M-tiles x 6 N-tiles
//    -> TCC fetch ~200MB -> ~80MB (A x4, B x2 instead of B x8).
// ---------------------------------------------------------------------------
#define QKV_N 6144
#define QKV_K 2048

__global__ __launch_bounds__(512, 2)
void gemm_qkv_256(const __hip_bfloat16* __restrict__ A,
                  const __hip_bfloat16* __restrict__ B,
                  __hip_bfloat16* __restrict__ C) {
  extern __shared__ char smem[];
  const int tid  = threadIdx.x;
  const int lane = tid & 63, w = tid >> 6;
  const int l15  = lane & 15, quad = lane >> 4;
  const int wm   = w >> 2, wn = w & 3;

  // XCD chunking: 192 blocks, c = XCD; chunk = 4 M-tiles x 6 N-tiles.
  const int orig = blockIdx.x;
  const int c   = orig & 7;
  const int idx = orig >> 3;              // 0..23
  const int by  = (c & 1) * 4 + idx / 6;  // 0..7
  const int bx  = (c >> 1) * 6 + idx % 6; // 0..23
  const int m0 = by * 256, n0 = bx * 256;

  // staging: chunk idx = round*512 + tid; row = idx>>2, q = idx&3 (16B chunks)
  // source col chunk pre-swizzled: q ^ ((row>>1)&3)
  const int ar0 = tid >> 2,         aq0 = (tid & 3) ^ ((ar0 >> 1) & 3);
  const int ar1 = (512 + tid) >> 2, aq1 = (tid & 3) ^ ((ar1 >> 1) & 3);
  const __hip_bfloat16* pA0 = A + (size_t)(m0 + ar0) * QKV_K + aq0 * 8;
  const __hip_bfloat16* pA1 = A + (size_t)(m0 + ar1) * QKV_K + aq1 * 8;
  const __hip_bfloat16* pB0 = B + (size_t)(n0 + ar0) * QKV_K + aq0 * 8;
  const __hip_bfloat16* pB1 = B + (size_t)(n0 + ar1) * QKV_K + aq1 * 8;
  const int dst0 = w * 1024;

  f32x4 acc[8][4];
#pragma unroll
  for (int mi = 0; mi < 8; ++mi)
#pragma unroll
    for (int ni = 0; ni < 4; ++ni) acc[mi][ni] = (f32x4){0.f, 0.f, 0.f, 0.f};

  // fragment read byte offsets (swizzled quad; (row>>1)&3 == (l15>>1)&3
  // because all row strides are multiples of 16)
  const int sq   = (l15 >> 1) & 3;
  const int aoff = ((wm * 128 + l15) * 32 + (quad ^ sq) * 8) * 2;
  const int boff = ((wn * 64 + l15) * 32 + (quad ^ sq) * 8) * 2;

#pragma unroll
  for (int p = 0; p < 3; ++p) {
    char* Sp = smem + p * 32768;
    gl_lds16(pA0 + p * 32, Sp + dst0);
    gl_lds16(pA1 + p * 32, Sp + dst0 + 8192);
    gl_lds16(pB0 + p * 32, Sp + 16384 + dst0);
    gl_lds16(pB1 + p * 32, Sp + 16384 + dst0 + 8192);
  }
  asm volatile("s_waitcnt vmcnt(8)\n\ts_barrier" ::: "memory");

  for (int tb = 0; tb < 64; tb += 4) {
#pragma unroll
    for (int u = 0; u < 4; ++u) {
      const int t  = tb + u;
      const char* As = smem + u * 32768;
      const char* Bs = As + 16384;
      const int tn = (t + 3) & 63;
      char* Sn = smem + ((u + 3) & 3) * 32768;

      short8 a[8];
#pragma unroll
      for (int mi = 0; mi < 8; ++mi)
        a[mi] = *(const short8*)(As + aoff + mi * 1024);
      short8 b0 = *(const short8*)(Bs + boff);
      short8 b1 = *(const short8*)(Bs + boff + 1024);
      gl_lds16(pA0 + tn * 32, Sn + dst0);
      gl_lds16(pA1 + tn * 32, Sn + dst0 + 8192);
      __builtin_amdgcn_s_barrier();
      __builtin_amdgcn_s_setprio(1);
#pragma unroll
      for (int mi = 0; mi < 8; ++mi) {
        acc[mi][0] = __builtin_amdgcn_mfma_f32_16x16x32_bf16(a[mi], b0, acc[mi][0], 0, 0, 0);
        acc[mi][1] = __builtin_amdgcn_mfma_f32_16x16x32_bf16(a[mi], b1, acc[mi][1], 0, 0, 0);
      }
      __builtin_amdgcn_s_setprio(0);
      __builtin_amdgcn_s_barrier();

      short8 b2 = *(const short8*)(Bs + boff + 2048);
      short8 b3 = *(const short8*)(Bs + boff + 3072);
      gl_lds16(pB0 + tn * 32, Sn + 16384 + dst0);
      gl_lds16(pB1 + tn * 32, Sn + 16384 + dst0 + 8192);
      asm volatile("s_waitcnt vmcnt(8)\n\ts_barrier" ::: "memory");
      __builtin_amdgcn_s_setprio(1);
#pragma unroll
      for (int mi = 0; mi < 8; ++mi) {
        acc[mi][2] = __builtin_amdgcn_mfma_f32_16x16x32_bf16(a[mi], b2, acc[mi][2], 0, 0, 0);
        acc[mi][3] = __builtin_amdgcn_mfma_f32_16x16x32_bf16(a[mi], b3, acc[mi][3], 0, 0, 0);
      }
      __builtin_amdgcn_s_setprio(0);
      __builtin_amdgcn_s_barrier();
    }
  }

  const int crow = m0 + wm * 128 + quad * 4;
  const int ccol = n0 + wn * 64 + l15;
#pragma unroll
  for (int mi = 0; mi < 8; ++mi)
#pragma unroll
    for (int ni = 0; ni < 4; ++ni)
#pragma unroll
      for (int r = 0; r < 4; ++r)
        C[(size_t)(crow + mi * 16 + r) * QKV_N + ccol + ni * 16] =
            __float2bfloat16(acc[mi][ni][r]);
}

// ---------------------------------------------------------------------------
// Epilogue: reads C[2048][6144] bf16 (L3-resident). Verified R1.
// ---------------------------------------------------------------------------
__global__ __launch_bounds__(256)
void qkv_epilogue(const __hip_bfloat16* __restrict__ C,
                  const float* __restrict__ q_scale, const float* __restrict__ k_scale,
                  const float* __restrict__ pe,
                  __hip_bfloat16* __restrict__ Qb, __hip_bfloat16* __restrict__ Kb,
                  __hip_bfloat16* __restrict__ Vt) {
  const int bid = blockIdx.x;
  const int t = threadIdx.x;
  if (bid < 512) {
    const int sec = bid >> 8;          // 0 = q, 1 = k
    const int h   = (bid >> 4) & 15;
    const int rb  = bid & 15;          // 16 row-blocks of 128
    const float* scale = sec ? k_scale : q_scale;
    const float qmul = sec ? 1.0f : 0.08838834764831845f;
    __hip_bfloat16* dst = sec ? Kb : Qb;

    const int row = t >> 1, half = t & 1;
    const int l = rb * 128 + row;
    const __hip_bfloat16* grow = C + (size_t)l * TDIM + sec * DIM + h * HD + half * 64;

    float ss = 0.f;
#pragma unroll
    for (int c8 = 0; c8 < 64; c8 += 8) {
      short8 v8 = *(const short8*)(grow + c8);
#pragma unroll
      for (int j = 0; j < 8; ++j) { float f = bits2f(v8[j]); ss += f * f; }
    }
    ss += __shfl_xor(ss, 1);
    const float rrms = rsqrtf(ss * (1.f / 128.f) + 1e-6f);

    const float* perow = pe + (size_t)l * 256 + half * 128;
    __hip_bfloat16* drow = dst + ((size_t)h * L_SEQ + l) * HD + half * 64;

#pragma unroll
    for (int c8 = 0; c8 < 64; c8 += 8) {
      short8 v8 = *(const short8*)(grow + c8);
      float f[8];
#pragma unroll
      for (int j = 0; j < 8; ++j)
        f[j] = bits2f(v8[j]) * rrms * scale[half * 64 + c8 + j];
      short8 o;
#pragma unroll
      for (int p = 0; p < 4; ++p) {
        float4 pp = *(const float4*)(perow + c8 * 2 + p * 4);
        float e = f[2 * p], od = f[2 * p + 1];
        o[2 * p]     = bf16bits((pp.x * e + pp.y * od) * qmul);
        o[2 * p + 1] = bf16bits((pp.z * e + pp.w * od) * qmul);
      }
      *(short8*)(drow + c8) = o;
    }
  } else {
    __shared__ short Tt[128 * 72];
    const int vb = bid - 512;
    const int h = vb >> 5, lb = vb & 31;
    const int l0 = lb * 64;
#pragma unroll
    for (int k = 0; k < 4; ++k) {
      int idx = t + k * 256;
      int row = idx >> 4, c = idx & 15;
      short8 v = *(const short8*)(C + (size_t)(l0 + row) * TDIM + 2 * DIM + h * HD + c * 8);
#pragma unroll
      for (int j = 0; j < 8; ++j) Tt[(c * 8 + j) * 72 + row] = v[j];
    }
    __syncthreads();
    const int d = t >> 1, lh = t & 1;
    __hip_bfloat16* vrow = Vt + ((size_t)h * HD + d) * L_SEQ + l0 + lh * 32;
#pragma unroll
    for (int k = 0; k < 4; ++k) {
      short8 o = *(const short8*)&Tt[d * 72 + lh * 32 + k * 8];
      *(short8*)(vrow + k * 8) = o;
    }
  }
}

// ---------------------------------------------------------------------------
// Proj GEMM, R5: deep-ring port of the verified R1 schedule to 128x128 tiles.
// 256 threads = 4 waves (2M x 2N, 64x64 each), BK=32, 4 x 16KB LDS ring,
// identical 2-phase / counted-vmcnt(8) skeleton, same LDS XOR swizzle.
// Grid 256 blocks = 1/CU. fp32 out + bias. Same MFMA order as old gemm_proj
// -> bit-identical accumulation.
// ---------------------------------------------------------------------------
#define PJ_N 2048
#define PJ_K 2048

__global__ __launch_bounds__(256, 2)
void gemm_proj_128(const __hip_bfloat16* __restrict__ A,
                   const __hip_bfloat16* __restrict__ B,
                   const float* __restrict__ bias, float* __restrict__ C) {
  __shared__ __align__(16) char smem[65536];
  const int tid  = threadIdx.x;
  const int lane = tid & 63, w = tid >> 6;
  const int l15  = lane & 15, quad = lane >> 4;
  const int wm   = (w >> 1) * 64, wn = (w & 1) * 64;

  // XCD chunking: 256 blocks over 16x16 tiles; chunk = 4 M x 8 N per XCD.
  const int orig = blockIdx.x;
  const int c   = orig & 7;
  const int idx = orig >> 3;                // 0..31
  const int by  = (c >> 1) * 4 + (idx & 3); // 0..15
  const int bx  = (c & 1) * 8 + (idx >> 2); // 0..15
  const int m0 = by * 128, n0 = bx * 128;

  // staging: A-tile 128x32 = 512 chunks; rounds 0,1: idx = r*256 + tid
  const int ar0 = tid >> 2,         aq0 = (tid & 3) ^ ((ar0 >> 1) & 3);
  const int ar1 = (256 + tid) >> 2, aq1 = (tid & 3) ^ ((ar1 >> 1) & 3);
  const __hip_bfloat16* pA0 = A + (size_t)(m0 + ar0) * PJ_K + aq0 * 8;
  const __hip_bfloat16* pA1 = A + (size_t)(m0 + ar1) * PJ_K + aq1 * 8;
  const __hip_bfloat16* pB0 = B + (size_t)(n0 + ar0) * PJ_K + aq0 * 8;
  const __hip_bfloat16* pB1 = B + (size_t)(n0 + ar1) * PJ_K + aq1 * 8;
  const int dst0 = w * 1024;   // round0 wave base; round1 at +4096

  f32x4 acc[4][4];
#pragma unroll
  for (int mi = 0; mi < 4; ++mi)
#pragma unroll
    for (int ni = 0; ni < 4; ++ni) acc[mi][ni] = (f32x4){0.f, 0.f, 0.f, 0.f};

  const int sq   = (l15 >> 1) & 3;
  const int aoff = ((wm + l15) * 32 + (quad ^ sq) * 8) * 2;
  const int boff = 8192 + ((wn + l15) * 32 + (quad ^ sq) * 8) * 2;

#pragma unroll
  for (int p = 0; p < 3; ++p) {
    char* Sp = smem + p * 16384;
    gl_lds16(pA0 + p * 32, Sp + dst0);
    gl_lds16(pA1 + p * 32, Sp + dst0 + 4096);
    gl_lds16(pB0 + p * 32, Sp + 8192 + dst0);
    gl_lds16(pB1 + p * 32, Sp + 8192 + dst0 + 4096);
  }
  asm volatile("s_waitcnt vmcnt(8)\n\ts_barrier" ::: "memory");

  for (int tb = 0; tb < 64; tb += 4) {
#pragma unroll
    for (int u = 0; u < 4; ++u) {
      const int t  = tb + u;
      const char* As = smem + u * 16384;
      const char* Bs = As;                       // boff carries +8192
      const int tn = (t + 3) & 63;
      char* Sn = smem + ((u + 3) & 3) * 16384;

      short8 a[4];
#pragma unroll
      for (int mi = 0; mi < 4; ++mi)
        a[mi] = *(const short8*)(As + aoff + mi * 1024);
      short8 b0 = *(const short8*)(Bs + boff);
      short8 b1 = *(const short8*)(Bs + boff + 1024);
      gl_lds16(pA0 + tn * 32, Sn + dst0);
      gl_lds16(pA1 + tn * 32, Sn + dst0 + 4096);
      __builtin_amdgcn_s_barrier();
      __builtin_amdgcn_s_setprio(1);
#pragma unroll
      for (int mi = 0; mi < 4; ++mi) {
        acc[mi][0] = __builtin_amdgcn_mfma_f32_16x16x32_bf16(a[mi], b0, acc[mi][0], 0, 0, 0);
        acc[mi][1] = __builtin_amdgcn_mfma_f32_16x16x32_bf16(a[mi], b1, acc[mi][1], 0, 0, 0);
      }
      __builtin_amdgcn_s_setprio(0);
      __builtin_amdgcn_s_barrier();

      short8 b2 = *(const short8*)(Bs + boff + 2048);
      short8 b3 = *(const short8*)(Bs + boff + 3072);
      gl_lds16(pB0 + tn * 32, Sn + 8192 + dst0);
      gl_lds16(pB1 + tn * 32, Sn + 8192 + dst0 + 4096);
      asm volatile("s_waitcnt vmcnt(8)\n\ts_barrier" ::: "memory");
      __builtin_amdgcn_s_setprio(1);
#pragma unroll
      for (int mi = 0; mi < 4; ++mi) {
        acc[mi][2] = __builtin_amdgcn_mfma_f32_16x16x32_bf16(a[mi], b2, acc[mi][2], 0, 0, 0);
        acc[mi][3] = __builtin_amdgcn_mfma_f32_16x16x32_bf16(a[mi], b3, acc[mi][3], 0, 0, 0);
      }
      __builtin_amdgcn_s_setprio(0);
      __builtin_amdgcn_s_barrier();
    }
  }

  const int crow = m0 + wm + quad * 4;
  const int ccol = n0 + wn + l15;
#pragma unroll
  for (int mi = 0; mi < 4; ++mi)
#pragma unroll
    for (int ni = 0; ni < 4; ++ni) {
      float bv = bias[ccol + ni * 16];
#pragma unroll
      for (int r = 0; r < 4; ++r)
        C[(size_t)(crow + mi * 16 + r) * PJ_N + ccol + ni * 16] =
            acc[mi][ni][r] + bv;
    }
}

// ---------------------------------------------------------------------------
// Flash attention v4 (verified R4): 32x32 swapped-QK^T, lane-local softmax,
// cvt_pk + permlane32_swap P redistribution, O^T via swizzled LDS store.
// ---------------------------------------------------------------------------
#define NZ 4
#define ZLEN (L_SEQ / NZ)

__global__ __launch_bounds__(256, 3)
void attn_mfma(const __hip_bfloat16* __restrict__ Qb,
               const __hip_bfloat16* __restrict__ Kb,
               const __hip_bfloat16* __restrict__ Vt,
               __hip_bfloat16* __restrict__ Opart, float2* __restrict__ ml) {
  const int orig = blockIdx.x;
  const int wg   = (orig & 7) * 128 + (orig >> 3);
  const int h    = wg >> 6;
  const int rem  = wg & 63;
  const int z    = rem >> 4;
  const int q0   = (rem & 15) * 128;
  const int t    = threadIdx.x;
  const int lane = t & 63, w = t >> 6;
  const int l31  = lane & 31;
  const int u    = lane >> 5;

  __shared__ __align__(16) __hip_bfloat16 Ks[64 * 128];
  __shared__ __align__(16) __hip_bfloat16 Vs[128 * 64];

  const __hip_bfloat16* kbase = Kb + (size_t)h * L_SEQ * HD;
  const __hip_bfloat16* vbase = Vt + (size_t)h * HD * L_SEQ;

  short8 aq[8];
  {
    const __hip_bfloat16* qb = Qb + ((size_t)h * L_SEQ + q0 + w * 32 + l31) * HD + u * 8;
#pragma unroll
    for (int hh = 0; hh < 8; ++hh)
      aq[hh] = *(const short8*)(qb + hh * 16);
  }

  f32x16 o[4];
#pragma unroll
  for (int dt = 0; dt < 4; ++dt)
#pragma unroll
    for (int r = 0; r < 16; ++r) o[dt][r] = 0.f;
  float m_run = -1e30f, l_run = 0.f;

  for (int kt = 0; kt < ZLEN / 64; ++kt) {
    const int k0 = z * ZLEN + kt * 64;
#pragma unroll
    for (int i = 0; i < 4; ++i) {
      int krow = w * 16 + i * 4 + (lane >> 4);
      int kch  = (lane & 15) ^ (krow & 7);
      gl_lds16(kbase + (size_t)(k0 + krow) * HD + kch * 8,
               &Ks[(w * 16 + i * 4) * 128]);
    }
#pragma unroll
    for (int i = 0; i < 4; ++i) {
      int vrow = w * 32 + i * 8 + (lane >> 3);
      int vch  = (lane & 7) ^ (vrow & 7);
      gl_lds16(vbase + (size_t)vrow * L_SEQ + k0 + vch * 8,
               &Vs[(w * 32 + i * 8) * 64]);
    }
    __syncthreads();

#pragma unroll
    for (int ks = 0; ks < 2; ++ks) {
      const int krow = ks * 32 + l31;
      const char* krowp = (const char*)Ks + krow * 256;
      const int ksw = krow & 7;
      f32x16 s;
#pragma unroll
      for (int r = 0; r < 16; ++r) s[r] = 0.f;
      __builtin_amdgcn_s_setprio(1);
#pragma unroll
      for (int hh = 0; hh < 8; ++hh) {
        short8 ak = *(const short8*)(krowp + ((hh * 2 + u) ^ ksw) * 16);
        s = __builtin_amdgcn_mfma_f32_32x32x16_bf16(ak, aq[hh], s, 0, 0, 0);
      }
      __builtin_amdgcn_s_setprio(0);

      float rm = s[0];
#pragma unroll
      for (int r = 1; r < 16; ++r) rm = fmaxf(rm, s[r]);
      rm = fmaxf(rm, __shfl_xor(rm, 32));

      if (!__all(rm <= m_run + 8.f)) {
        float mnew = fmaxf(m_run, rm);
        float alpha = __expf(m_run - mnew);
        m_run = mnew;
        l_run *= alpha;
#pragma unroll
        for (int dt = 0; dt < 4; ++dt)
#pragma unroll
          for (int r = 0; r < 16; ++r) o[dt][r] *= alpha;
      }

      float sum = 0.f;
#pragma unroll
      for (int r = 0; r < 16; ++r) {
        float p = __expf(s[r] - m_run);
        s[r] = p;
        sum += p;
      }
      sum += __shfl_xor(sum, 32);
      l_run += sum;

      unsigned int W0 = pack_bf16(s[0],  s[1]),  W1 = pack_bf16(s[2],  s[3]);
      unsigned int W2 = pack_bf16(s[4],  s[5]),  W3 = pack_bf16(s[6],  s[7]);
      unsigned int W4 = pack_bf16(s[8],  s[9]),  W5 = pack_bf16(s[10], s[11]);
      unsigned int W6 = pack_bf16(s[12], s[13]), W7 = pack_bf16(s[14], s[15]);
      asm("v_permlane32_swap_b32 %0, %1" : "+v"(W0), "+v"(W2));
      asm("v_permlane32_swap_b32 %0, %1" : "+v"(W1), "+v"(W3));
      asm("v_permlane32_swap_b32 %0, %1" : "+v"(W4), "+v"(W6));
      asm("v_permlane32_swap_b32 %0, %1" : "+v"(W5), "+v"(W7));
      u32x4 pb0 = {W0, W1, W2, W3};
      u32x4 pb1 = {W4, W5, W6, W7};
      short8 ap0 = *(short8*)&pb0;
      short8 ap1 = *(short8*)&pb1;

      __builtin_amdgcn_s_setprio(1);
#pragma unroll
      for (int dt = 0; dt < 4; ++dt) {
        const int d = dt * 32 + l31;
        const char* vrowp = (const char*)Vs + d * 128;
        const int vsw = d & 7;
        short8 av0 = *(const short8*)(vrowp + ((ks * 4 + u) ^ vsw) * 16);
        o[dt] = __builtin_amdgcn_mfma_f32_32x32x16_bf16(av0, ap0, o[dt], 0, 0, 0);
        short8 av1 = *(const short8*)(vrowp + ((ks * 4 + 2 + u) ^ vsw) * 16);
        o[dt] = __builtin_amdgcn_mfma_f32_32x32x16_bf16(av1, ap1, o[dt], 0, 0, 0);
      }
      __builtin_amdgcn_s_setprio(0);
    }
    __syncthreads();
  }

  const float linv = 1.f / l_run;
  char* Ot = (char*)Ks + w * 8192;
  const int qsw = l31 & 7;
#pragma unroll
  for (int dt = 0; dt < 4; ++dt)
#pragma unroll
    for (int p = 0; p < 8; ++p) {
      unsigned int v = pack_bf16(o[dt][2 * p] * linv, o[dt][2 * p + 1] * linv);
      int dpair = dt * 16 + (p & 1) + (p >> 1) * 4 + 2 * u;
      *(unsigned int*)(Ot + l31 * 256 + ((dpair >> 2) ^ qsw) * 16 + (dpair & 3) * 4) = v;
    }
  __syncthreads();
  {
    const int qr = lane >> 1, half = lane & 1;
    const char* Orow = (char*)Ks + w * 8192 + qr * 256;
    __hip_bfloat16* gout =
        Opart + ((size_t)(z * NH + h) * L_SEQ + q0 + w * 32 + qr) * HD;
#pragma unroll
    for (int c8 = 0; c8 < 8; ++c8) {
      int chunk = half * 8 + c8;
      short8 v = *(const short8*)(Orow + ((chunk ^ (qr & 7)) * 16));
      *(short8*)(gout + chunk * 8) = v;
    }
  }
  if (lane < 32) {
    size_t rb = (size_t)(z * NH + h) * L_SEQ + q0 + w * 32;
    ml[rb + l31] = make_float2(m_run, l_run);
  }
}

// ---------------------------------------------------------------------------
// Combine the four KV-split chunks. Verified R3.
// ---------------------------------------------------------------------------
__global__ __launch_bounds__(256)
void attn_combine4(const __hip_bfloat16* __restrict__ Opart,
                   const float2* __restrict__ ml,
                   __hip_bfloat16* __restrict__ out) {
  const int h  = blockIdx.y;
  const int q  = blockIdx.x * 16 + (threadIdx.x >> 4);
  const int d8 = (threadIdx.x & 15) * 8;
  size_t idx[NZ];
  float2 a[NZ];
#pragma unroll
  for (int zz = 0; zz < NZ; ++zz) {
    idx[zz] = ((size_t)zz * NH + h) * L_SEQ + q;
    a[zz] = ml[idx[zz]];
  }
  float M = fmaxf(fmaxf(a[0].x, a[1].x), fmaxf(a[2].x, a[3].x));
  float wz[NZ];
  float tot = 0.f;
#pragma unroll
  for (int zz = 0; zz < NZ; ++zz) {
    wz[zz] = __expf(a[zz].x - M) * a[zz].y;
    tot += wz[zz];
  }
  float inv = 1.f / tot;
  float acc[8] = {0.f, 0.f, 0.f, 0.f, 0.f, 0.f, 0.f, 0.f};
#pragma unroll
  for (int zz = 0; zz < NZ; ++zz) {
    short8 ov = *(const short8*)&Opart[idx[zz] * HD + d8];
#pragma unroll
    for (int j = 0; j < 8; ++j) acc[j] += wz[zz] * bits2f(ov[j]);
  }
  short8 r;
#pragma unroll
  for (int j = 0; j < 8; ++j) r[j] = bf16bits(acc[j] * inv);
  *(short8*)&out[(size_t)q * DIM + h * HD + d8] = r;
}

// ---------------------------------------------------------------------------
extern "C" void kernel_launch(void* const* d_in, const int* in_sizes, int n_in,
                              void* d_out, int out_size, void* d_ws, size_t ws_size,
                              hipStream_t stream) {
  const float* x       = (const float*)d_in[0];
  const float* pe      = (const float*)d_in[1];
  const float* qkv_w   = (const float*)d_in[2];
  const float* q_scale = (const float*)d_in[3];
  const float* k_scale = (const float*)d_in[4];
  const float* proj_w  = (const float*)d_in[5];
  const float* proj_b  = (const float*)d_in[6];
  float* out = (float*)d_out;

  // Workspace (67,108,864 B), phase-disjoint reuse:
  //  p1 cast+gemm:  xb [0,8.4M) | wb [8.4,33.6M) | Cq [33.6,58.8M)
  //  p2 epilogue:   reads Cq; Qb [0,8.4M) Kb [8.4,16.8M) Vt [16.8,25.2M)
  //  p3 attn z=4:   reads Qb/Kb/Vt; Opart [33.6,67.1M), ml [25.2,26.2M)
  //  p4 combine:    reads Opart/ml; attn_out [0,8.4M) (over dead Qb)
  //  p5 cast_pw:    pwb [33.6,42.0M) (over dead Opart)  -- AFTER combine
  //  p6 proj:       reads attn_out + pwb; writes out
  char* base = (char*)d_ws;
  __hip_bfloat16* xb       = (__hip_bfloat16*)base;
  __hip_bfloat16* wb       = (__hip_bfloat16*)(base + 8388608);
  __hip_bfloat16* Cq       = (__hip_bfloat16*)(base + 33554432);
  __hip_bfloat16* Qb       = (__hip_bfloat16*)base;
  __hip_bfloat16* Kb       = (__hip_bfloat16*)(base + 8388608);
  __hip_bfloat16* Vt       = (__hip_bfloat16*)(base + 16777216);
  __hip_bfloat16* Opart    = (__hip_bfloat16*)(base + 33554432);
  float2*         ml       = (float2*)(base + 25165824);
  __hip_bfloat16* attn_out = (__hip_bfloat16*)base;
  __hip_bfloat16* pwb      = (__hip_bfloat16*)(base + 33554432);

  static bool attr_done = false;
  if (!attr_done) {
    hipFuncSetAttribute((const void*)gemm_qkv_256,
                        hipFuncAttributeMaxDynamicSharedMemorySize, 131072);
    attr_done = true;
  }

  cast2_bf16<<<dim3((DIM * DIM + TDIM * DIM) / (256 * 8)), 256, 0, stream>>>(
      x, xb, qkv_w, wb);

  gemm_qkv_256<<<dim3((TDIM / 256) * (L_SEQ / 256)), 512, 131072, stream>>>(xb, wb, Cq);

  qkv_epilogue<<<dim3(1024), 256, 0, stream>>>(Cq, q_scale, k_scale, pe, Qb, Kb, Vt);

  attn_mfma<<<dim3(NZ * NH * (L_SEQ / 128)), 256, 0, stream>>>(Qb, Kb, Vt, Opart, ml);

  attn_combine4<<<dim3(L_SEQ / 16, NH), 256, 0, stream>>>(Opart, ml, attn_out);

  cast_bf16<<<dim3(DIM * DIM / (256 * 8)), 256, 0, stream>>>(proj_w, pwb, DIM * DIM);

  gemm_proj_128<<<dim3(256), 256, 0, stream>>>(attn_out, pwb, proj_b, out);
}

// Round 6
// 281.129 us; speedup vs baseline: 1.2139x; 1.0268x over previous
//
#include <hip/hip_runtime.h>
#include <hip/hip_bf16.h>
#include <math.h>

#define L_SEQ 2048
#define DIM   2048
#define NH    16
#define HD    128
#define TDIM  6144

typedef __attribute__((ext_vector_type(8))) short short8;
typedef __attribute__((ext_vector_type(4))) float f32x4;
typedef __attribute__((ext_vector_type(16))) float f32x16;
typedef __attribute__((ext_vector_type(4))) unsigned int u32x4;

// async global->LDS, 16 B per lane. LDS dest = wave-uniform base + lane*16.
__device__ __forceinline__ void gl_lds16(const void* g, void* l) {
  __builtin_amdgcn_global_load_lds(
      (const __attribute__((address_space(1))) unsigned int*)g,
      (__attribute__((address_space(3))) unsigned int*)l, 16, 0, 0);
}

__device__ __forceinline__ short bf16bits(float x) {
  __hip_bfloat16 h = __float2bfloat16(x);
  return *(short*)&h;
}

__device__ __forceinline__ float bits2f(short s) {
  unsigned int u = ((unsigned int)(unsigned short)s) << 16;
  return __uint_as_float(u);
}

__device__ __forceinline__ unsigned int pack_bf16(float a, float b) {
  __hip_bfloat162 h = __float22bfloat162_rn(make_float2(a, b));
  return *(unsigned int*)&h;
}

// ---------------------------------------------------------------------------
// fused fp32 -> bf16 cast of x (4M), qkv_w (12M), proj_w (4M) in one launch.
// ---------------------------------------------------------------------------
__global__ __launch_bounds__(256)
void cast3_bf16(const float* __restrict__ a, __hip_bfloat16* __restrict__ oa,
                const float* __restrict__ b, __hip_bfloat16* __restrict__ ob,
                const float* __restrict__ c, __hip_bfloat16* __restrict__ oc) {
  int i = (blockIdx.x * 256 + threadIdx.x) * 8;
  const float* src;
  __hip_bfloat16* dst;
  int off;
  if (i < DIM * DIM)                  { src = a; dst = oa; off = i; }
  else if (i < DIM * DIM + TDIM * DIM){ src = b; dst = ob; off = i - DIM * DIM; }
  else                                { src = c; dst = oc; off = i - DIM * DIM - TDIM * DIM; }
  float4 v0 = *(const float4*)(src + off);
  float4 v1 = *(const float4*)(src + off + 4);
  short8 o;
  o[0] = bf16bits(v0.x); o[1] = bf16bits(v0.y); o[2] = bf16bits(v0.z); o[3] = bf16bits(v0.w);
  o[4] = bf16bits(v1.x); o[5] = bf16bits(v1.y); o[6] = bf16bits(v1.z); o[7] = bf16bits(v1.w);
  *(short8*)(dst + off) = o;
}

// ---------------------------------------------------------------------------
// QKV GEMM, R6: BM=256 x BN=192 tiles -> 8x32 = 256 blocks = exactly 1/CU
// (R5's 256x256 grid was 192 blocks: 25% of CUs idle).
// Same verified 2-phase / ring-4 / counted-vmcnt skeleton + LDS XOR swizzle.
// B tile = 192 rows = 1.5 staging rounds: all waves do round 0, waves 0-3 do
// round 1 -> per-wave loads/tile: w<4: 4, w>=4: 3 -> per-wave counted vmcnt
// (8 vs 6), same invariant (wait publishes tile t+1, keeps t+2/t+3 in flight).
// LDS: 4 x (16K A + 12K B) = 112 KB dynamic.
// XCD chunk: 4 M-tiles x 8 N-tiles per XCD (A-panel 4 MB, L2-resident).
// ---------------------------------------------------------------------------
#define QKV_N 6144
#define QKV_K 2048

__global__ __launch_bounds__(512, 2)
void gemm_qkv_256(const __hip_bfloat16* __restrict__ A,
                  const __hip_bfloat16* __restrict__ B,
                  __hip_bfloat16* __restrict__ C) {
  extern __shared__ char smem[];
  const int tid  = threadIdx.x;
  const int lane = tid & 63, w = tid >> 6;
  const int l15  = lane & 15, quad = lane >> 4;
  const int wm   = w >> 2, wn = w & 3;

  // 256 blocks over 8 M x 32 N tiles; XCD c owns by in [ (c>>2)*4, +4 ),
  // bx in [ (c&3)*8, +8 ).
  const int orig = blockIdx.x;
  const int c   = orig & 7;
  const int idx = orig >> 3;                 // 0..31
  const int by  = (c >> 2) * 4 + (idx >> 3); // 0..7
  const int bx  = (c & 3) * 8 + (idx & 7);   // 0..31
  const int m0 = by * 256, n0 = bx * 192;

  // staging rows/quads (source pre-swizzled: q ^ ((row>>1)&3))
  const int ar0 = tid >> 2,         aq0 = (tid & 3) ^ ((ar0 >> 1) & 3);
  const int ar1 = (512 + tid) >> 2, aq1 = (tid & 3) ^ ((ar1 >> 1) & 3);
  const __hip_bfloat16* pA0 = A + (size_t)(m0 + ar0) * QKV_K + aq0 * 8;
  const __hip_bfloat16* pA1 = A + (size_t)(m0 + ar1) * QKV_K + aq1 * 8;
  const __hip_bfloat16* pB0 = B + (size_t)(n0 + ar0) * QKV_K + aq0 * 8; // rows 0-127
  const __hip_bfloat16* pB1 = B + (size_t)(n0 + ar1) * QKV_K + aq1 * 8; // rows 128-191 (tid<256 only)
  const int dst0 = w * 1024;

  f32x4 acc[8][3];
#pragma unroll
  for (int mi = 0; mi < 8; ++mi)
#pragma unroll
    for (int ni = 0; ni < 3; ++ni) acc[mi][ni] = (f32x4){0.f, 0.f, 0.f, 0.f};

  // fragment read offsets (swizzled quad; rows == l15 mod 16 -> sq invariant)
  const int sq   = (l15 >> 1) & 3;
  const int aoff = ((wm * 128 + l15) * 32 + (quad ^ sq) * 8) * 2;
  const int boff = 16384 + ((wn * 48 + l15) * 32 + (quad ^ sq) * 8) * 2;

  // prologue: stage tiles 0,1,2 (buffer stride 28672 B)
#pragma unroll
  for (int p = 0; p < 3; ++p) {
    char* Sp = smem + p * 28672;
    gl_lds16(pA0 + p * 32, Sp + dst0);
    gl_lds16(pA1 + p * 32, Sp + dst0 + 8192);
    gl_lds16(pB0 + p * 32, Sp + 16384 + dst0);
    if (w < 4) gl_lds16(pB1 + p * 32, Sp + 24576 + dst0);
  }
  if (w < 4) asm volatile("s_waitcnt vmcnt(8)" ::: "memory");
  else       asm volatile("s_waitcnt vmcnt(6)" ::: "memory");
  __builtin_amdgcn_s_barrier();

  for (int tb = 0; tb < 64; tb += 4) {
#pragma unroll
    for (int u = 0; u < 4; ++u) {
      const int t  = tb + u;
      const char* As = smem + (u & 3) * 28672;
      const char* Bs = As;                      // boff carries +16384
      const int tn = (t + 3) & 63;
      char* Sn = smem + ((u + 3) & 3) * 28672;

      // ---- phase A: A-frags + b0,b1; stage A(t+3); MFMA ni=0,1 ----
      short8 a[8];
#pragma unroll
      for (int mi = 0; mi < 8; ++mi)
        a[mi] = *(const short8*)(As + aoff + mi * 1024);
      short8 b0 = *(const short8*)(Bs + boff);
      short8 b1 = *(const short8*)(Bs + boff + 1024);
      gl_lds16(pA0 + tn * 32, Sn + dst0);
      gl_lds16(pA1 + tn * 32, Sn + dst0 + 8192);
      __builtin_amdgcn_s_barrier();
      __builtin_amdgcn_s_setprio(1);
#pragma unroll
      for (int mi = 0; mi < 8; ++mi) {
        acc[mi][0] = __builtin_amdgcn_mfma_f32_16x16x32_bf16(a[mi], b0, acc[mi][0], 0, 0, 0);
        acc[mi][1] = __builtin_amdgcn_mfma_f32_16x16x32_bf16(a[mi], b1, acc[mi][1], 0, 0, 0);
      }
      __builtin_amdgcn_s_setprio(0);
      __builtin_amdgcn_s_barrier();

      // ---- phase B: b2; stage B(t+3); counted wait publishes t+1 ----
      short8 b2 = *(const short8*)(Bs + boff + 2048);
      gl_lds16(pB0 + tn * 32, Sn + 16384 + dst0);
      if (w < 4) {
        gl_lds16(pB1 + tn * 32, Sn + 24576 + dst0);
        asm volatile("s_waitcnt vmcnt(8)" ::: "memory");
      } else {
        asm volatile("s_waitcnt vmcnt(6)" ::: "memory");
      }
      __builtin_amdgcn_s_barrier();
      __builtin_amdgcn_s_setprio(1);
#pragma unroll
      for (int mi = 0; mi < 8; ++mi)
        acc[mi][2] = __builtin_amdgcn_mfma_f32_16x16x32_bf16(a[mi], b2, acc[mi][2], 0, 0, 0);
      __builtin_amdgcn_s_setprio(0);
      __builtin_amdgcn_s_barrier();
    }
  }

  const int crow = m0 + wm * 128 + quad * 4;
  const int ccol = n0 + wn * 48 + l15;
#pragma unroll
  for (int mi = 0; mi < 8; ++mi)
#pragma unroll
    for (int ni = 0; ni < 3; ++ni)
#pragma unroll
      for (int r = 0; r < 4; ++r)
        C[(size_t)(crow + mi * 16 + r) * QKV_N + ccol + ni * 16] =
            __float2bfloat16(acc[mi][ni][r]);
}

// ---------------------------------------------------------------------------
// Epilogue: reads C[2048][6144] bf16 (L3-resident). Verified R1.
// ---------------------------------------------------------------------------
__global__ __launch_bounds__(256)
void qkv_epilogue(const __hip_bfloat16* __restrict__ C,
                  const float* __restrict__ q_scale, const float* __restrict__ k_scale,
                  const float* __restrict__ pe,
                  __hip_bfloat16* __restrict__ Qb, __hip_bfloat16* __restrict__ Kb,
                  __hip_bfloat16* __restrict__ Vt) {
  const int bid = blockIdx.x;
  const int t = threadIdx.x;
  if (bid < 512) {
    const int sec = bid >> 8;          // 0 = q, 1 = k
    const int h   = (bid >> 4) & 15;
    const int rb  = bid & 15;          // 16 row-blocks of 128
    const float* scale = sec ? k_scale : q_scale;
    const float qmul = sec ? 1.0f : 0.08838834764831845f;
    __hip_bfloat16* dst = sec ? Kb : Qb;

    const int row = t >> 1, half = t & 1;
    const int l = rb * 128 + row;
    const __hip_bfloat16* grow = C + (size_t)l * TDIM + sec * DIM + h * HD + half * 64;

    float ss = 0.f;
#pragma unroll
    for (int c8 = 0; c8 < 64; c8 += 8) {
      short8 v8 = *(const short8*)(grow + c8);
#pragma unroll
      for (int j = 0; j < 8; ++j) { float f = bits2f(v8[j]); ss += f * f; }
    }
    ss += __shfl_xor(ss, 1);
    const float rrms = rsqrtf(ss * (1.f / 128.f) + 1e-6f);

    const float* perow = pe + (size_t)l * 256 + half * 128;
    __hip_bfloat16* drow = dst + ((size_t)h * L_SEQ + l) * HD + half * 64;

#pragma unroll
    for (int c8 = 0; c8 < 64; c8 += 8) {
      short8 v8 = *(const short8*)(grow + c8);
      float f[8];
#pragma unroll
      for (int j = 0; j < 8; ++j)
        f[j] = bits2f(v8[j]) * rrms * scale[half * 64 + c8 + j];
      short8 o;
#pragma unroll
      for (int p = 0; p < 4; ++p) {
        float4 pp = *(const float4*)(perow + c8 * 2 + p * 4);
        float e = f[2 * p], od = f[2 * p + 1];
        o[2 * p]     = bf16bits((pp.x * e + pp.y * od) * qmul);
        o[2 * p + 1] = bf16bits((pp.z * e + pp.w * od) * qmul);
      }
      *(short8*)(drow + c8) = o;
    }
  } else {
    __shared__ short Tt[128 * 72];
    const int vb = bid - 512;
    const int h = vb >> 5, lb = vb & 31;
    const int l0 = lb * 64;
#pragma unroll
    for (int k = 0; k < 4; ++k) {
      int idx = t + k * 256;
      int row = idx >> 4, c = idx & 15;
      short8 v = *(const short8*)(C + (size_t)(l0 + row) * TDIM + 2 * DIM + h * HD + c * 8);
#pragma unroll
      for (int j = 0; j < 8; ++j) Tt[(c * 8 + j) * 72 + row] = v[j];
    }
    __syncthreads();
    const int d = t >> 1, lh = t & 1;
    __hip_bfloat16* vrow = Vt + ((size_t)h * HD + d) * L_SEQ + l0 + lh * 32;
#pragma unroll
    for (int k = 0; k < 4; ++k) {
      short8 o = *(const short8*)&Tt[d * 72 + lh * 32 + k * 8];
      *(short8*)(vrow + k * 8) = o;
    }
  }
}

// ---------------------------------------------------------------------------
// Proj GEMM (verified R5): deep-ring 128x128, 256 blocks = 1/CU.
// ---------------------------------------------------------------------------
#define PJ_N 2048
#define PJ_K 2048

__global__ __launch_bounds__(256, 2)
void gemm_proj_128(const __hip_bfloat16* __restrict__ A,
                   const __hip_bfloat16* __restrict__ B,
                   const float* __restrict__ bias, float* __restrict__ C) {
  __shared__ __align__(16) char smem[65536];
  const int tid  = threadIdx.x;
  const int lane = tid & 63, w = tid >> 6;
  const int l15  = lane & 15, quad = lane >> 4;
  const int wm   = (w >> 1) * 64, wn = (w & 1) * 64;

  const int orig = blockIdx.x;
  const int c   = orig & 7;
  const int idx = orig >> 3;                // 0..31
  const int by  = (c >> 1) * 4 + (idx & 3); // 0..15
  const int bx  = (c & 1) * 8 + (idx >> 2); // 0..15
  const int m0 = by * 128, n0 = bx * 128;

  const int ar0 = tid >> 2,         aq0 = (tid & 3) ^ ((ar0 >> 1) & 3);
  const int ar1 = (256 + tid) >> 2, aq1 = (tid & 3) ^ ((ar1 >> 1) & 3);
  const __hip_bfloat16* pA0 = A + (size_t)(m0 + ar0) * PJ_K + aq0 * 8;
  const __hip_bfloat16* pA1 = A + (size_t)(m0 + ar1) * PJ_K + aq1 * 8;
  const __hip_bfloat16* pB0 = B + (size_t)(n0 + ar0) * PJ_K + aq0 * 8;
  const __hip_bfloat16* pB1 = B + (size_t)(n0 + ar1) * PJ_K + aq1 * 8;
  const int dst0 = w * 1024;

  f32x4 acc[4][4];
#pragma unroll
  for (int mi = 0; mi < 4; ++mi)
#pragma unroll
    for (int ni = 0; ni < 4; ++ni) acc[mi][ni] = (f32x4){0.f, 0.f, 0.f, 0.f};

  const int sq   = (l15 >> 1) & 3;
  const int aoff = ((wm + l15) * 32 + (quad ^ sq) * 8) * 2;
  const int boff = 8192 + ((wn + l15) * 32 + (quad ^ sq) * 8) * 2;

#pragma unroll
  for (int p = 0; p < 3; ++p) {
    char* Sp = smem + p * 16384;
    gl_lds16(pA0 + p * 32, Sp + dst0);
    gl_lds16(pA1 + p * 32, Sp + dst0 + 4096);
    gl_lds16(pB0 + p * 32, Sp + 8192 + dst0);
    gl_lds16(pB1 + p * 32, Sp + 8192 + dst0 + 4096);
  }
  asm volatile("s_waitcnt vmcnt(8)\n\ts_barrier" ::: "memory");

  for (int tb = 0; tb < 64; tb += 4) {
#pragma unroll
    for (int u = 0; u < 4; ++u) {
      const int t  = tb + u;
      const char* As = smem + u * 16384;
      const char* Bs = As;
      const int tn = (t + 3) & 63;
      char* Sn = smem + ((u + 3) & 3) * 16384;

      short8 a[4];
#pragma unroll
      for (int mi = 0; mi < 4; ++mi)
        a[mi] = *(const short8*)(As + aoff + mi * 1024);
      short8 b0 = *(const short8*)(Bs + boff);
      short8 b1 = *(const short8*)(Bs + boff + 1024);
      gl_lds16(pA0 + tn * 32, Sn + dst0);
      gl_lds16(pA1 + tn * 32, Sn + dst0 + 4096);
      __builtin_amdgcn_s_barrier();
      __builtin_amdgcn_s_setprio(1);
#pragma unroll
      for (int mi = 0; mi < 4; ++mi) {
        acc[mi][0] = __builtin_amdgcn_mfma_f32_16x16x32_bf16(a[mi], b0, acc[mi][0], 0, 0, 0);
        acc[mi][1] = __builtin_amdgcn_mfma_f32_16x16x32_bf16(a[mi], b1, acc[mi][1], 0, 0, 0);
      }
      __builtin_amdgcn_s_setprio(0);
      __builtin_amdgcn_s_barrier();

      short8 b2 = *(const short8*)(Bs + boff + 2048);
      short8 b3 = *(const short8*)(Bs + boff + 3072);
      gl_lds16(pB0 + tn * 32, Sn + 8192 + dst0);
      gl_lds16(pB1 + tn * 32, Sn + 8192 + dst0 + 4096);
      asm volatile("s_waitcnt vmcnt(8)\n\ts_barrier" ::: "memory");
      __builtin_amdgcn_s_setprio(1);
#pragma unroll
      for (int mi = 0; mi < 4; ++mi) {
        acc[mi][2] = __builtin_amdgcn_mfma_f32_16x16x32_bf16(a[mi], b2, acc[mi][2], 0, 0, 0);
        acc[mi][3] = __builtin_amdgcn_mfma_f32_16x16x32_bf16(a[mi], b3, acc[mi][3], 0, 0, 0);
      }
      __builtin_amdgcn_s_setprio(0);
      __builtin_amdgcn_s_barrier();
    }
  }

  const int crow = m0 + wm + quad * 4;
  const int ccol = n0 + wn + l15;
#pragma unroll
  for (int mi = 0; mi < 4; ++mi)
#pragma unroll
    for (int ni = 0; ni < 4; ++ni) {
      float bv = bias[ccol + ni * 16];
#pragma unroll
      for (int r = 0; r < 4; ++r)
        C[(size_t)(crow + mi * 16 + r) * PJ_N + ccol + ni * 16] =
            acc[mi][ni][r] + bv;
    }
}

// ---------------------------------------------------------------------------
// Flash attention v4 (verified R4): 32x32 swapped-QK^T, lane-local softmax,
// cvt_pk + permlane32_swap P redistribution, O^T via swizzled LDS store.
// ---------------------------------------------------------------------------
#define NZ 4
#define ZLEN (L_SEQ / NZ)

__global__ __launch_bounds__(256, 3)
void attn_mfma(const __hip_bfloat16* __restrict__ Qb,
               const __hip_bfloat16* __restrict__ Kb,
               const __hip_bfloat16* __restrict__ Vt,
               __hip_bfloat16* __restrict__ Opart, float2* __restrict__ ml) {
  const int orig = blockIdx.x;
  const int wg   = (orig & 7) * 128 + (orig >> 3);
  const int h    = wg >> 6;
  const int rem  = wg & 63;
  const int z    = rem >> 4;
  const int q0   = (rem & 15) * 128;
  const int t    = threadIdx.x;
  const int lane = t & 63, w = t >> 6;
  const int l31  = lane & 31;
  const int u    = lane >> 5;

  __shared__ __align__(16) __hip_bfloat16 Ks[64 * 128];
  __shared__ __align__(16) __hip_bfloat16 Vs[128 * 64];

  const __hip_bfloat16* kbase = Kb + (size_t)h * L_SEQ * HD;
  const __hip_bfloat16* vbase = Vt + (size_t)h * HD * L_SEQ;

  short8 aq[8];
  {
    const __hip_bfloat16* qb = Qb + ((size_t)h * L_SEQ + q0 + w * 32 + l31) * HD + u * 8;
#pragma unroll
    for (int hh = 0; hh < 8; ++hh)
      aq[hh] = *(const short8*)(qb + hh * 16);
  }

  f32x16 o[4];
#pragma unroll
  for (int dt = 0; dt < 4; ++dt)
#pragma unroll
    for (int r = 0; r < 16; ++r) o[dt][r] = 0.f;
  float m_run = -1e30f, l_run = 0.f;

  for (int kt = 0; kt < ZLEN / 64; ++kt) {
    const int k0 = z * ZLEN + kt * 64;
#pragma unroll
    for (int i = 0; i < 4; ++i) {
      int krow = w * 16 + i * 4 + (lane >> 4);
      int kch  = (lane & 15) ^ (krow & 7);
      gl_lds16(kbase + (size_t)(k0 + krow) * HD + kch * 8,
               &Ks[(w * 16 + i * 4) * 128]);
    }
#pragma unroll
    for (int i = 0; i < 4; ++i) {
      int vrow = w * 32 + i * 8 + (lane >> 3);
      int vch  = (lane & 7) ^ (vrow & 7);
      gl_lds16(vbase + (size_t)vrow * L_SEQ + k0 + vch * 8,
               &Vs[(w * 32 + i * 8) * 64]);
    }
    __syncthreads();

#pragma unroll
    for (int ks = 0; ks < 2; ++ks) {
      const int krow = ks * 32 + l31;
      const char* krowp = (const char*)Ks + krow * 256;
      const int ksw = krow & 7;
      f32x16 s;
#pragma unroll
      for (int r = 0; r < 16; ++r) s[r] = 0.f;
      __builtin_amdgcn_s_setprio(1);
#pragma unroll
      for (int hh = 0; hh < 8; ++hh) {
        short8 ak = *(const short8*)(krowp + ((hh * 2 + u) ^ ksw) * 16);
        s = __builtin_amdgcn_mfma_f32_32x32x16_bf16(ak, aq[hh], s, 0, 0, 0);
      }
      __builtin_amdgcn_s_setprio(0);

      float rm = s[0];
#pragma unroll
      for (int r = 1; r < 16; ++r) rm = fmaxf(rm, s[r]);
      rm = fmaxf(rm, __shfl_xor(rm, 32));

      if (!__all(rm <= m_run + 8.f)) {
        float mnew = fmaxf(m_run, rm);
        float alpha = __expf(m_run - mnew);
        m_run = mnew;
        l_run *= alpha;
#pragma unroll
        for (int dt = 0; dt < 4; ++dt)
#pragma unroll
          for (int r = 0; r < 16; ++r) o[dt][r] *= alpha;
      }

      float sum = 0.f;
#pragma unroll
      for (int r = 0; r < 16; ++r) {
        float p = __expf(s[r] - m_run);
        s[r] = p;
        sum += p;
      }
      sum += __shfl_xor(sum, 32);
      l_run += sum;

      unsigned int W0 = pack_bf16(s[0],  s[1]),  W1 = pack_bf16(s[2],  s[3]);
      unsigned int W2 = pack_bf16(s[4],  s[5]),  W3 = pack_bf16(s[6],  s[7]);
      unsigned int W4 = pack_bf16(s[8],  s[9]),  W5 = pack_bf16(s[10], s[11]);
      unsigned int W6 = pack_bf16(s[12], s[13]), W7 = pack_bf16(s[14], s[15]);
      asm("v_permlane32_swap_b32 %0, %1" : "+v"(W0), "+v"(W2));
      asm("v_permlane32_swap_b32 %0, %1" : "+v"(W1), "+v"(W3));
      asm("v_permlane32_swap_b32 %0, %1" : "+v"(W4), "+v"(W6));
      asm("v_permlane32_swap_b32 %0, %1" : "+v"(W5), "+v"(W7));
      u32x4 pb0 = {W0, W1, W2, W3};
      u32x4 pb1 = {W4, W5, W6, W7};
      short8 ap0 = *(short8*)&pb0;
      short8 ap1 = *(short8*)&pb1;

      __builtin_amdgcn_s_setprio(1);
#pragma unroll
      for (int dt = 0; dt < 4; ++dt) {
        const int d = dt * 32 + l31;
        const char* vrowp = (const char*)Vs + d * 128;
        const int vsw = d & 7;
        short8 av0 = *(const short8*)(vrowp + ((ks * 4 + u) ^ vsw) * 16);
        o[dt] = __builtin_amdgcn_mfma_f32_32x32x16_bf16(av0, ap0, o[dt], 0, 0, 0);
        short8 av1 = *(const short8*)(vrowp + ((ks * 4 + 2 + u) ^ vsw) * 16);
        o[dt] = __builtin_amdgcn_mfma_f32_32x32x16_bf16(av1, ap1, o[dt], 0, 0, 0);
      }
      __builtin_amdgcn_s_setprio(0);
    }
    __syncthreads();
  }

  const float linv = 1.f / l_run;
  char* Ot = (char*)Ks + w * 8192;
  const int qsw = l31 & 7;
#pragma unroll
  for (int dt = 0; dt < 4; ++dt)
#pragma unroll
    for (int p = 0; p < 8; ++p) {
      unsigned int v = pack_bf16(o[dt][2 * p] * linv, o[dt][2 * p + 1] * linv);
      int dpair = dt * 16 + (p & 1) + (p >> 1) * 4 + 2 * u;
      *(unsigned int*)(Ot + l31 * 256 + ((dpair >> 2) ^ qsw) * 16 + (dpair & 3) * 4) = v;
    }
  __syncthreads();
  {
    const int qr = lane >> 1, half = lane & 1;
    const char* Orow = (char*)Ks + w * 8192 + qr * 256;
    __hip_bfloat16* gout =
        Opart + ((size_t)(z * NH + h) * L_SEQ + q0 + w * 32 + qr) * HD;
#pragma unroll
    for (int c8 = 0; c8 < 8; ++c8) {
      int chunk = half * 8 + c8;
      short8 v = *(const short8*)(Orow + ((chunk ^ (qr & 7)) * 16));
      *(short8*)(gout + chunk * 8) = v;
    }
  }
  if (lane < 32) {
    size_t rb = (size_t)(z * NH + h) * L_SEQ + q0 + w * 32;
    ml[rb + l31] = make_float2(m_run, l_run);
  }
}

// ---------------------------------------------------------------------------
// Combine the four KV-split chunks. Verified R3.
// ---------------------------------------------------------------------------
__global__ __launch_bounds__(256)
void attn_combine4(const __hip_bfloat16* __restrict__ Opart,
                   const float2* __restrict__ ml,
                   __hip_bfloat16* __restrict__ out) {
  const int h  = blockIdx.y;
  const int q  = blockIdx.x * 16 + (threadIdx.x >> 4);
  const int d8 = (threadIdx.x & 15) * 8;
  size_t idx[NZ];
  float2 a[NZ];
#pragma unroll
  for (int zz = 0; zz < NZ; ++zz) {
    idx[zz] = ((size_t)zz * NH + h) * L_SEQ + q;
    a[zz] = ml[idx[zz]];
  }
  float M = fmaxf(fmaxf(a[0].x, a[1].x), fmaxf(a[2].x, a[3].x));
  float wz[NZ];
  float tot = 0.f;
#pragma unroll
  for (int zz = 0; zz < NZ; ++zz) {
    wz[zz] = __expf(a[zz].x - M) * a[zz].y;
    tot += wz[zz];
  }
  float inv = 1.f / tot;
  float acc[8] = {0.f, 0.f, 0.f, 0.f, 0.f, 0.f, 0.f, 0.f};
#pragma unroll
  for (int zz = 0; zz < NZ; ++zz) {
    short8 ov = *(const short8*)&Opart[idx[zz] * HD + d8];
#pragma unroll
    for (int j = 0; j < 8; ++j) acc[j] += wz[zz] * bits2f(ov[j]);
  }
  short8 r;
#pragma unroll
  for (int j = 0; j < 8; ++j) r[j] = bf16bits(acc[j] * inv);
  *(short8*)&out[(size_t)q * DIM + h * HD + d8] = r;
}

// ---------------------------------------------------------------------------
extern "C" void kernel_launch(void* const* d_in, const int* in_sizes, int n_in,
                              void* d_out, int out_size, void* d_ws, size_t ws_size,
                              hipStream_t stream) {
  const float* x       = (const float*)d_in[0];
  const float* pe      = (const float*)d_in[1];
  const float* qkv_w   = (const float*)d_in[2];
  const float* q_scale = (const float*)d_in[3];
  const float* k_scale = (const float*)d_in[4];
  const float* proj_w  = (const float*)d_in[5];
  const float* proj_b  = (const float*)d_in[6];
  float* out = (float*)d_out;

  // Workspace (67,108,864 B), phase-disjoint reuse:
  //  p1 cast3+gemm: xb [0,8.4M) | wb [8.4,33.6M) | pwb [25.2,33.6M)?? NO --
  //                 pwb [25.2,33.6M) would overlap wb [8.4,33.6M).
  //                 wb = 12M elems * 2B = 25.2MB -> wb [8.4,33.6M). pwb must
  //                 not overlap wb: place pwb AFTER Cq region is chosen.
  //  Layout: xb [0,8.4M) | wb [8.4,33.6M) | Cq [33.6,58.8M) | pwb [58.8,67.1M)
  //  p2 epilogue:   reads Cq; Qb [0,8.4M) Kb [8.4,16.8M) Vt [16.8,25.2M)
  //  p3 attn z=4:   Opart [25.2,58.8M) (dead wb-tail + Cq), ml -> d_out scratch
  //  p4 combine:    attn_out [58.8-?] no -- attn_out [0,8.4M) over dead Qb
  //  p5 proj:       reads attn_out + pwb [58.8,67.1M); writes out
  char* base = (char*)d_ws;
  __hip_bfloat16* xb       = (__hip_bfloat16*)base;
  __hip_bfloat16* wb       = (__hip_bfloat16*)(base + 8388608);
  __hip_bfloat16* Cq       = (__hip_bfloat16*)(base + 33554432);
  __hip_bfloat16* pwb      = (__hip_bfloat16*)(base + 58720256);
  __hip_bfloat16* Qb       = (__hip_bfloat16*)base;
  __hip_bfloat16* Kb       = (__hip_bfloat16*)(base + 8388608);
  __hip_bfloat16* Vt       = (__hip_bfloat16*)(base + 16777216);
  __hip_bfloat16* Opart    = (__hip_bfloat16*)(base + 25165824);  // 33.5MB, ends 58.7M
  float2*         ml       = (float2*)d_out;                       // scratch until proj
  __hip_bfloat16* attn_out = (__hip_bfloat16*)base;

  static bool attr_done = false;
  if (!attr_done) {
    hipFuncSetAttribute((const void*)gemm_qkv_256,
                        hipFuncAttributeMaxDynamicSharedMemorySize, 131072);
    attr_done = true;
  }

  cast3_bf16<<<dim3((2 * DIM * DIM + TDIM * DIM) / (256 * 8)), 256, 0, stream>>>(
      x, xb, qkv_w, wb, proj_w, pwb);

  gemm_qkv_256<<<dim3(256), 512, 114688, stream>>>(xb, wb, Cq);

  qkv_epilogue<<<dim3(1024), 256, 0, stream>>>(Cq, q_scale, k_scale, pe, Qb, Kb, Vt);

  attn_mfma<<<dim3(NZ * NH * (L_SEQ / 128)), 256, 0, stream>>>(Qb, Kb, Vt, Opart, ml);

  attn_combine4<<<dim3(L_SEQ / 16, NH), 256, 0, stream>>>(Opart, ml, attn_out);

  gemm_proj_128<<<dim3(256), 256, 0, stream>>>(attn_out, pwb, proj_b, out);
}